// Round 8
// baseline (187.404 us; speedup 1.0000x reference)
//
#include <hip/hip_runtime.h>
#include <math.h>

#define BB 4
#define DL 150
#define PL 1000
#define CD 64
#define NC1 40
#define NC2 80
#define NC3 160
#define L1O 997
#define L2O 990
#define L3O 979
#define L1P 1000
#define L2P 992
#define L3P 980
#define DLP 152
#define PLP 984
#define NINF (-1e30f)

__device__ __forceinline__ float relu_(float x){ return fmaxf(x, 0.f); }
__device__ __forceinline__ float lrelu_(float x){ return x > 0.f ? x : 0.01f * x; }

__device__ __forceinline__ unsigned fenc(float x){
  unsigned u = __float_as_uint(x);
  return (u & 0x80000000u) ? ~u : (u | 0x80000000u);
}
__device__ __forceinline__ float fdec(unsigned u){
  return __uint_as_float((u & 0x80000000u) ? (u & 0x7fffffffu) : ~u);
}
__device__ __forceinline__ float4 relu4_(float4 v){
  v.x = fmaxf(v.x, 0.f); v.y = fmaxf(v.y, 0.f);
  v.z = fmaxf(v.z, 0.f); v.w = fmaxf(v.w, 0.f);
  return v;
}

// ---- proj table ----
__global__ void k_proj(const float* __restrict__ emb, const float* __restrict__ w1,
                       float* __restrict__ projG){
  int e = blockIdx.x * 256 + threadIdx.x;
  if (e >= 26 * 160) return;
  int tok = e / 160, rem = e % 160, k = rem / 40, co = rem % 40;
  float a = 0.f;
  const float* er = emb + tok * CD;
  const float* wr = w1 + co * (CD * 4) + k;
  #pragma unroll 8
  for (int ci = 0; ci < CD; ci++) a = fmaf(er[ci], wr[ci * 4], a);
  projG[tok * 161 + k * 40 + co] = a;
}

// ---- conv1 apply (writes relu'd h1) ----
__global__ __launch_bounds__(256) void k_conv1(const int* __restrict__ prot,
                        const float* __restrict__ projG, const float* __restrict__ b1,
                        float* __restrict__ h1){
  __shared__ float sp[26 * 161];
  int b = blockIdx.x / 80;
  int t = (blockIdx.x % 80) * 256 + threadIdx.x;
  for (int k = threadIdx.x; k < 26 * 161; k += 256) sp[k] = projG[k];
  __syncthreads();
  int p = t & 1023, co2 = t >> 10;
  if (p >= L1O) return;
  const int* pr = prot + b * PL + p;
  int t0 = pr[0], t1 = pr[1], t2 = pr[2], t3 = pr[3];
  #pragma unroll
  for (int c = 0; c < 2; c++){
    int co = co2 * 2 + c;
    float a = b1[co] + sp[t0 * 161 + co] + sp[t1 * 161 + 40 + co]
            + sp[t2 * 161 + 80 + co] + sp[t3 * 161 + 120 + co];
    h1[(size_t)(b * NC1 + co) * L1P + p] = relu_(a);
  }
}

// ---- conv2: LDS whole-K tiled (unchanged) ----
#define C2XW 44
#define C2WP 324
__global__ __launch_bounds__(128) void k_c2(const float* __restrict__ h1,
                        const float* __restrict__ w, const float* __restrict__ bias,
                        float* __restrict__ h2){
  __shared__ float xs[NC1 * C2XW];
  __shared__ float wl[16 * C2WP];
  int blk = blockIdx.x;
  int pt = blk % 31; int t = blk / 31;
  int cog = t % 5; int b = t / 5;
  int co0 = cog * 16, pblk = pt * 32;
  int tid = threadIdx.x;
  const float* xb = h1 + (size_t)(b * NC1) * L1P + pblk;
  for (int i = tid; i < 440; i += 128){
    int r = i / 11, c = i % 11;
    *(float4*)(&xs[r * C2XW + c * 4]) = *(const float4*)(xb + (size_t)r * L1P + c * 4);
  }
  for (int i = tid; i < 1280; i += 128){
    int cc = i / 80, c = i % 80;
    *(float4*)(&wl[cc * C2WP + c * 4]) =
        *(const float4*)(w + (size_t)(co0 + cc) * 320 + c * 4);
  }
  __syncthreads();
  int co_l = tid >> 3, pg = tid & 7, p0 = pg * 4;
  float acc[4] = {0,0,0,0};
  const float* wc = &wl[co_l * C2WP];
  #pragma unroll 2
  for (int ci = 0; ci < NC1; ci++){
    const float* xrow = &xs[ci * C2XW + p0];
    float xv[12];
    *(float4*)(&xv[0]) = *(const float4*)(xrow);
    *(float4*)(&xv[4]) = *(const float4*)(xrow + 4);
    *(float4*)(&xv[8]) = *(const float4*)(xrow + 8);
    float wk[8];
    *(float4*)(&wk[0]) = *(const float4*)(wc + ci * 8);
    *(float4*)(&wk[4]) = *(const float4*)(wc + ci * 8 + 4);
    #pragma unroll
    for (int k = 0; k < 8; k++){
      #pragma unroll
      for (int pp = 0; pp < 4; pp++)
        acc[pp] = fmaf(xv[pp + k], wk[k], acc[pp]);
    }
  }
  int co = co0 + co_l;
  float bv = bias[co];
  int pbase = pblk + p0;
  float* yr = h2 + (size_t)(b * NC2 + co) * L2P + pbase;
  if (pbase + 3 < L2O){
    float4 o; o.x = relu_(acc[0] + bv); o.y = relu_(acc[1] + bv);
    o.z = relu_(acc[2] + bv); o.w = relu_(acc[3] + bv);
    *(float4*)yr = o;
  } else {
    #pragma unroll
    for (int pp = 0; pp < 4; pp++)
      if (pbase + pp < L2O) yr[pp] = relu_(acc[pp] + bv);
  }
}

// ---- conv3: split-K(2), 16co x 128p tile, 8p/thread, 3 blocks/CU ----
// grid 640 = b(4) x cog(10) x pt(8) x half(2); 256 thr
#define C3XP 140
#define C3WPP 484
__global__ __launch_bounds__(256) void k_c3(const float* __restrict__ h2,
                        const float* __restrict__ w, const float* __restrict__ bias,
                        float* __restrict__ pA, float* __restrict__ pB){
  __shared__ float xs[40 * C3XP];             // 22.4 KB
  __shared__ float wl[16 * C3WPP];            // 31.0 KB
  int blk = blockIdx.x;
  int half = blk & 1; int t = blk >> 1;
  int pt = t & 7; t >>= 3;
  int cog = t % 10; int b = t / 10;
  int co0 = cog * 16, pblk = pt * 128, ci0 = half * 40;
  int tid = threadIdx.x;
  const float* xb = h2 + (size_t)(b * NC2 + ci0) * L2P + pblk;
  for (int i = tid; i < 1400; i += 256){      // 40 rows x 35 f4 (140 cols)
    int r = i / 35, c = i % 35;
    *(float4*)(&xs[r * C3XP + c * 4]) = *(const float4*)(xb + (size_t)r * L2P + c * 4);
  }
  const float* wb = w + (size_t)co0 * 960 + ci0 * 12;
  for (int i = tid; i < 1920; i += 256){      // 16 co x 120 f4
    int cc = i / 120, c = i % 120;
    *(float4*)(&wl[cc * C3WPP + c * 4]) =
        *(const float4*)(wb + (size_t)cc * 960 + c * 4);
  }
  __syncthreads();
  int co_l = tid >> 4, pg = tid & 15, p0 = pg * 8;
  float acc[8] = {0,0,0,0,0,0,0,0};
  const float* wc = &wl[co_l * C3WPP];
  #pragma unroll 2
  for (int ci = 0; ci < 40; ci++){
    const float* xrow = &xs[ci * C3XP + p0];
    float xv[20];
    *(float4*)(&xv[0])  = *(const float4*)(xrow);
    *(float4*)(&xv[4])  = *(const float4*)(xrow + 4);
    *(float4*)(&xv[8])  = *(const float4*)(xrow + 8);
    *(float4*)(&xv[12]) = *(const float4*)(xrow + 12);
    *(float4*)(&xv[16]) = *(const float4*)(xrow + 16);
    float wk[12];
    *(float4*)(&wk[0]) = *(const float4*)(wc + ci * 12);
    *(float4*)(&wk[4]) = *(const float4*)(wc + ci * 12 + 4);
    *(float4*)(&wk[8]) = *(const float4*)(wc + ci * 12 + 8);
    #pragma unroll
    for (int k = 0; k < 12; k++){
      #pragma unroll
      for (int pp = 0; pp < 8; pp++)
        acc[pp] = fmaf(xv[pp + k], wk[k], acc[pp]);
    }
  }
  int co = co0 + co_l;
  float bv = (half == 0) ? bias[co] : 0.f;
  float* yr = (half == 0 ? pA : pB) + (size_t)(b * NC3 + co) * L3P;
  int pbase = pblk + p0;
  if (pbase + 7 < L3O){
    float4 o0, o1;
    o0.x = acc[0] + bv; o0.y = acc[1] + bv; o0.z = acc[2] + bv; o0.w = acc[3] + bv;
    o1.x = acc[4] + bv; o1.y = acc[5] + bv; o1.z = acc[6] + bv; o1.w = acc[7] + bv;
    *(float4*)(yr + pbase) = o0; *(float4*)(yr + pbase + 4) = o1;
  } else {
    #pragma unroll
    for (int pp = 0; pp < 8; pp++)
      if (pbase + pp < L3O) yr[pbase + pp] = acc[pp] + bv;
  }
}

// ---- fused: blocks 0..159 drug-att (+enc init); blocks 160..799 protein-att ----
__global__ __launch_bounds__(128) void k_dpatt(const float* __restrict__ drug,
                        const int* __restrict__ natoms,
                        const float* __restrict__ Wd, const float* __restrict__ bd,
                        float* __restrict__ dattT, unsigned* __restrict__ enc,
                        const float* __restrict__ pA, const float* __restrict__ pB,
                        const int* __restrict__ prot,
                        const float* __restrict__ Wp, const float* __restrict__ bp,
                        float* __restrict__ pattT){
  __shared__ float xs[160 * 68];
  __shared__ float wl[16 * 164];
  int blk = blockIdx.x;
  int tid = threadIdx.x;
  if (blk < 160){
    if (blk == 0){
      for (int k = tid; k < 2 * BB * NC3; k += 128) enc[k] = 0u;
    }
    int b = blk / 40, c0 = (blk % 40) * 4;
    for (int i = tid; i < DL; i += 128){
      const float4* xr = (const float4*)(drug + ((size_t)b * DL + i) * NC3);
      float4 a[4];
      #pragma unroll
      for (int cc = 0; cc < 4; cc++) a[cc] = make_float4(0.f, 0.f, 0.f, 0.f);
      for (int k4 = 0; k4 < 40; k4++){
        float4 xv = xr[k4];
        #pragma unroll
        for (int cc = 0; cc < 4; cc++){
          float4 wv = ((const float4*)(Wd + (size_t)(c0 + cc) * NC3))[k4];
          a[cc].x = fmaf(xv.x, wv.x, a[cc].x);
          a[cc].y = fmaf(xv.y, wv.y, a[cc].y);
          a[cc].z = fmaf(xv.z, wv.z, a[cc].z);
          a[cc].w = fmaf(xv.w, wv.w, a[cc].w);
        }
      }
      bool act = i < natoms[b];
      #pragma unroll
      for (int cc = 0; cc < 4; cc++){
        float r = act ? (a[cc].x + a[cc].y + a[cc].z + a[cc].w + bd[c0 + cc]) : 0.f;
        dattT[(size_t)(b * NC3 + c0 + cc) * DLP + i] = r;
      }
    }
    return;
  }
  int q = blk - 160;
  int jt = q & 15; int t = q >> 4;
  int cog = t % 10; int b = t / 10;
  int co0 = cog * 16, j0t = jt * 64;
  const float* xbA = pA + (size_t)(b * NC3) * L3P + j0t;
  const float* xbB = pB + (size_t)(b * NC3) * L3P + j0t;
  for (int i = tid; i < 2720; i += 128){
    int r = i / 17, c = i % 17;
    float4 vA = *(const float4*)(xbA + (size_t)r * L3P + c * 4);
    float4 vB = *(const float4*)(xbB + (size_t)r * L3P + c * 4);
    float4 v; v.x = vA.x + vB.x; v.y = vA.y + vB.y;
    v.z = vA.z + vB.z; v.w = vA.w + vB.w;
    *(float4*)(&xs[r * 68 + c * 4]) = relu4_(v);
  }
  for (int i = tid; i < 640; i += 128){
    int cc = i / 40, c = i % 40;
    *(float4*)(&wl[cc * 164 + c * 4]) =
        *(const float4*)(Wp + (size_t)(co0 + cc) * NC3 + c * 4);
  }
  __syncthreads();
  int cp = tid >> 4, jg = tid & 15;
  int j0 = jg * 4;
  float acc0[4] = {0,0,0,0}, acc1[4] = {0,0,0,0};
  const float* xcol = xs + j0;
  const float* w0r = wl + (cp * 2) * 164;
  const float* w1r = wl + (cp * 2 + 1) * 164;
  #pragma unroll 2
  for (int k4 = 0; k4 < 40; k4++){
    float4 wa = *(const float4*)(w0r + k4 * 4);
    float4 wb = *(const float4*)(w1r + k4 * 4);
    float4 x0 = *(const float4*)(xcol + (k4 * 4 + 0) * 68);
    float4 x1 = *(const float4*)(xcol + (k4 * 4 + 1) * 68);
    float4 x2 = *(const float4*)(xcol + (k4 * 4 + 2) * 68);
    float4 x3 = *(const float4*)(xcol + (k4 * 4 + 3) * 68);
    acc0[0] = fmaf(x0.x, wa.x, fmaf(x1.x, wa.y, fmaf(x2.x, wa.z, fmaf(x3.x, wa.w, acc0[0]))));
    acc0[1] = fmaf(x0.y, wa.x, fmaf(x1.y, wa.y, fmaf(x2.y, wa.z, fmaf(x3.y, wa.w, acc0[1]))));
    acc0[2] = fmaf(x0.z, wa.x, fmaf(x1.z, wa.y, fmaf(x2.z, wa.z, fmaf(x3.z, wa.w, acc0[2]))));
    acc0[3] = fmaf(x0.w, wa.x, fmaf(x1.w, wa.y, fmaf(x2.w, wa.z, fmaf(x3.w, wa.w, acc0[3]))));
    acc1[0] = fmaf(x0.x, wb.x, fmaf(x1.x, wb.y, fmaf(x2.x, wb.z, fmaf(x3.x, wb.w, acc1[0]))));
    acc1[1] = fmaf(x0.y, wb.x, fmaf(x1.y, wb.y, fmaf(x2.y, wb.z, fmaf(x3.y, wb.w, acc1[1]))));
    acc1[2] = fmaf(x0.z, wb.x, fmaf(x1.z, wb.y, fmaf(x2.z, wb.z, fmaf(x3.z, wb.w, acc1[2]))));
    acc1[3] = fmaf(x0.w, wb.x, fmaf(x1.w, wb.y, fmaf(x2.w, wb.z, fmaf(x3.w, wb.w, acc1[3]))));
  }
  int coA = co0 + cp * 2, coB = coA + 1;
  float bA = bp[coA], bB = bp[coB];
  int jb = j0t + j0;
  const int* pr = prot + b * PL;
  #pragma unroll
  for (int qq = 0; qq < 4; qq++){
    int j = jb + qq;
    if (j < L3O){
      bool act = pr[j] > 0;
      pattT[(size_t)(b * NC3 + coA) * PLP + j] = act ? (acc0[qq] + bA) : 0.f;
      pattT[(size_t)(b * NC3 + coB) * PLP + j] = act ? (acc1[qq] + bB) : 0.f;
    }
  }
}

// ---- means, rebalanced: all 256 threads work both phases ----
__global__ __launch_bounds__(256) void k_means(const float* __restrict__ dattT,
                        const float* __restrict__ pattT,
                        float* __restrict__ cmeanT, float* __restrict__ pmeanT){
  __shared__ float sda[DLP];
  __shared__ float spa[PLP];
  __shared__ float scm[4][DLP];
  int b = blockIdx.x / NC3, c = blockIdx.x % NC3;
  int tid = threadIdx.x;
  const float4* dr = (const float4*)(dattT + (size_t)(b * NC3 + c) * DLP);
  const float4* pr = (const float4*)(pattT + (size_t)(b * NC3 + c) * PLP);
  if (tid < DLP / 4) *(float4*)(&sda[tid * 4]) = dr[tid];
  if (tid < PLP / 4) *(float4*)(&spa[tid * 4]) = pr[tid];
  __syncthreads();
  // cmean partials: 600 tasks = 150 i x 4 j-quarters
  for (int t = tid; t < 600; t += 256){
    int i = t >> 2, qq = t & 3;
    int js = qq * 245, je = (qq == 3) ? L3O : js + 245;
    float v = sda[i];
    float s0 = 0.f, s1 = 0.f;
    int j = js;
    for (; j + 1 < je; j += 2){
      s0 += relu_(v + spa[j]);
      s1 += relu_(v + spa[j + 1]);
    }
    if (j < je) s0 += relu_(v + spa[j]);
    scm[qq][i] = s0 + s1;
  }
  // pmean: all threads over j
  for (int j = tid; j < L3O; j += 256){
    float v = spa[j];
    float s0 = 0.f, s1 = 0.f;
    #pragma unroll 2
    for (int i = 0; i < DL; i += 2){
      s0 += relu_(v + sda[i]);
      s1 += relu_(v + sda[i + 1]);
    }
    pmeanT[(size_t)(b * NC3 + c) * PLP + j] = (s0 + s1) * (1.f / DL);
  }
  __syncthreads();
  if (tid < DL){
    float s = scm[0][tid] + scm[1][tid] + scm[2][tid] + scm[3][tid];
    cmeanT[(size_t)(b * NC3 + c) * DLP + tid] = s * (1.f / L3O);
  }
}

// ---- fused gates: blocks 0..159 compound; 160..799 protein ----
__global__ __launch_bounds__(128) void k_atte(const float* __restrict__ cmeanT,
                        const float* __restrict__ pmeanT,
                        const float* __restrict__ Watt, const float* __restrict__ batt,
                        const float* __restrict__ drug,
                        const float* __restrict__ pA, const float* __restrict__ pB,
                        unsigned* __restrict__ enc){
  __shared__ float xs[160 * 68];
  __shared__ float wl[16 * 164];
  int blk = blockIdx.x;
  int tid = threadIdx.x;
  if (blk < 160){
    __shared__ float sred[2][4];
    int b = blk / 40, c0 = (blk % 40) * 4;
    float m[4];
    #pragma unroll
    for (int cc = 0; cc < 4; cc++) m[cc] = NINF;
    for (int i = tid; i < DL; i += 128){
      float acc[4];
      #pragma unroll
      for (int cc = 0; cc < 4; cc++) acc[cc] = batt[c0 + cc];
      const float* xc = cmeanT + (size_t)b * NC3 * DLP + i;
      const float* wr = Watt + (size_t)c0 * NC3;
      for (int cb = 0; cb < NC3; cb += 32){
        float xv[32];
        #pragma unroll
        for (int u = 0; u < 32; u++) xv[u] = xc[(size_t)(cb + u) * DLP];
        #pragma unroll
        for (int u = 0; u < 32; u++){
          #pragma unroll
          for (int cc = 0; cc < 4; cc++)
            acc[cc] = fmaf(xv[u], wr[(size_t)cc * NC3 + cb + u], acc[cc]);
        }
      }
      const float* gr = drug + ((size_t)b * DL + i) * NC3 + c0;
      #pragma unroll
      for (int cc = 0; cc < 4; cc++){
        float atte = 1.f / (1.f + expf(-acc[cc]));
        m[cc] = fmaxf(m[cc], gr[cc] * (0.5f + atte));
      }
    }
    int wave = tid >> 6, lane = tid & 63;
    #pragma unroll
    for (int cc = 0; cc < 4; cc++){
      float v = m[cc];
      for (int off = 1; off < 64; off <<= 1) v = fmaxf(v, __shfl_xor(v, off, 64));
      if (lane == 0) sred[wave][cc] = v;
    }
    __syncthreads();
    if (tid < 4){
      float v = fmaxf(sred[0][tid], sred[1][tid]);
      atomicMax(&enc[b * NC3 + c0 + tid], fenc(v));
    }
    return;
  }
  int q = blk - 160;
  int jt = q & 15; int t = q >> 4;
  int cog = t % 10; int b = t / 10;
  int co0 = cog * 16, j0t = jt * 64;
  const float* xb = pmeanT + (size_t)(b * NC3) * PLP + j0t;
  for (int i = tid; i < 2720; i += 128){
    int r = i / 17, c = i % 17;
    *(float4*)(&xs[r * 68 + c * 4]) = *(const float4*)(xb + (size_t)r * PLP + c * 4);
  }
  for (int i = tid; i < 640; i += 128){
    int cc = i / 40, c = i % 40;
    *(float4*)(&wl[cc * 164 + c * 4]) =
        *(const float4*)(Watt + (size_t)(co0 + cc) * NC3 + c * 4);
  }
  __syncthreads();
  int cp = tid >> 4, jg = tid & 15;
  int j0 = jg * 4;
  float acc0[4] = {0,0,0,0}, acc1[4] = {0,0,0,0};
  const float* xcol = xs + j0;
  const float* w0r = wl + (cp * 2) * 164;
  const float* w1r = wl + (cp * 2 + 1) * 164;
  #pragma unroll 2
  for (int k4 = 0; k4 < 40; k4++){
    float4 wa = *(const float4*)(w0r + k4 * 4);
    float4 wb = *(const float4*)(w1r + k4 * 4);
    float4 x0 = *(const float4*)(xcol + (k4 * 4 + 0) * 68);
    float4 x1 = *(const float4*)(xcol + (k4 * 4 + 1) * 68);
    float4 x2 = *(const float4*)(xcol + (k4 * 4 + 2) * 68);
    float4 x3 = *(const float4*)(xcol + (k4 * 4 + 3) * 68);
    acc0[0] = fmaf(x0.x, wa.x, fmaf(x1.x, wa.y, fmaf(x2.x, wa.z, fmaf(x3.x, wa.w, acc0[0]))));
    acc0[1] = fmaf(x0.y, wa.x, fmaf(x1.y, wa.y, fmaf(x2.y, wa.z, fmaf(x3.y, wa.w, acc0[1]))));
    acc0[2] = fmaf(x0.z, wa.x, fmaf(x1.z, wa.y, fmaf(x2.z, wa.z, fmaf(x3.z, wa.w, acc0[2]))));
    acc0[3] = fmaf(x0.w, wa.x, fmaf(x1.w, wa.y, fmaf(x2.w, wa.z, fmaf(x3.w, wa.w, acc0[3]))));
    acc1[0] = fmaf(x0.x, wb.x, fmaf(x1.x, wb.y, fmaf(x2.x, wb.z, fmaf(x3.x, wb.w, acc1[0]))));
    acc1[1] = fmaf(x0.y, wb.x, fmaf(x1.y, wb.y, fmaf(x2.y, wb.z, fmaf(x3.y, wb.w, acc1[1]))));
    acc1[2] = fmaf(x0.z, wb.x, fmaf(x1.z, wb.y, fmaf(x2.z, wb.z, fmaf(x3.z, wb.w, acc1[2]))));
    acc1[3] = fmaf(x0.w, wb.x, fmaf(x1.w, wb.y, fmaf(x2.w, wb.z, fmaf(x3.w, wb.w, acc1[3]))));
  }
  int coA = co0 + cp * 2, coB = coA + 1;
  float bA = batt[coA], bB = batt[coB];
  int jb = j0t + j0;
  float mA = NINF, mB = NINF;
  if (jb < L3P){
    const float* rA0 = pA + (size_t)(b * NC3 + coA) * L3P + jb;
    const float* rB0 = pB + (size_t)(b * NC3 + coA) * L3P + jb;
    const float* rA1 = pA + (size_t)(b * NC3 + coB) * L3P + jb;
    const float* rB1 = pB + (size_t)(b * NC3 + coB) * L3P + jb;
    float4 a0 = *(const float4*)rA0, b0 = *(const float4*)rB0;
    float4 a1 = *(const float4*)rA1, b1v = *(const float4*)rB1;
    float pAr[4] = {a0.x + b0.x, a0.y + b0.y, a0.z + b0.z, a0.w + b0.w};
    float pBr[4] = {a1.x + b1v.x, a1.y + b1v.y, a1.z + b1v.z, a1.w + b1v.w};
    #pragma unroll
    for (int qq = 0; qq < 4; qq++){
      int j = jb + qq;
      if (j < L3O){
        float gA = 1.f / (1.f + expf(-(acc0[qq] + bA)));
        float gB = 1.f / (1.f + expf(-(acc1[qq] + bB)));
        mA = fmaxf(mA, relu_(pAr[qq]) * (0.5f + gA));
        mB = fmaxf(mB, relu_(pBr[qq]) * (0.5f + gB));
      }
    }
  }
  #pragma unroll
  for (int off = 1; off < 16; off <<= 1){
    mA = fmaxf(mA, __shfl_xor(mA, off, 64));
    mB = fmaxf(mB, __shfl_xor(mB, off, 64));
  }
  if (jg == 0){
    atomicMax(&enc[BB * NC3 + b * NC3 + coA], fenc(mA));
    atomicMax(&enc[BB * NC3 + b * NC3 + coB], fenc(mB));
  }
}

// ---- MLP 1: 320 -> 1024 ----
__global__ __launch_bounds__(256) void k_mlp1(const unsigned* __restrict__ enc,
                        const float* __restrict__ W1, const float* __restrict__ bf1,
                        float* __restrict__ f1){
  int b = blockIdx.x >> 6, og = blockIdx.x & 63;
  int o = og * 16 + (threadIdx.x >> 4);
  int q = threadIdx.x & 15;
  const float4* wr = (const float4*)(W1 + (size_t)o * 320);
  float4 a = make_float4(0.f, 0.f, 0.f, 0.f);
  #pragma unroll
  for (int mi = 0; mi < 5; mi++){
    int k4 = q + mi * 16;
    int k = k4 * 4;
    const unsigned* e = (k < 160) ? (enc + b * NC3 + k)
                                  : (enc + BB * NC3 + b * NC3 + (k - 160));
    float4 wv = wr[k4];
    a.x = fmaf(fdec(e[0]), wv.x, a.x);
    a.y = fmaf(fdec(e[1]), wv.y, a.y);
    a.z = fmaf(fdec(e[2]), wv.z, a.z);
    a.w = fmaf(fdec(e[3]), wv.w, a.w);
  }
  float r = a.x + a.y + a.z + a.w;
  r += __shfl_xor(r, 1, 64); r += __shfl_xor(r, 2, 64);
  r += __shfl_xor(r, 4, 64); r += __shfl_xor(r, 8, 64);
  if (q == 0) f1[b * 1024 + o] = lrelu_(r + bf1[o]);
}

// ---- MLP 2: 1024 -> 1024 ----
__global__ __launch_bounds__(256) void k_mlp2(const float* __restrict__ x,
                        const float* __restrict__ W, const float* __restrict__ bias,
                        float* __restrict__ y){
  int b = blockIdx.x >> 6, og = blockIdx.x & 63;
  int o = og * 16 + (threadIdx.x >> 4);
  int q = threadIdx.x & 15;
  const float4* wr = (const float4*)(W + (size_t)o * 1024);
  const float4* xr = (const float4*)(x + b * 1024);
  float4 a = make_float4(0.f, 0.f, 0.f, 0.f);
  #pragma unroll
  for (int mi = 0; mi < 16; mi++){
    int k4 = q + mi * 16;
    float4 wv = wr[k4], xv = xr[k4];
    a.x = fmaf(xv.x, wv.x, a.x);
    a.y = fmaf(xv.y, wv.y, a.y);
    a.z = fmaf(xv.z, wv.z, a.z);
    a.w = fmaf(xv.w, wv.w, a.w);
  }
  float r = a.x + a.y + a.z + a.w;
  r += __shfl_xor(r, 1, 64); r += __shfl_xor(r, 2, 64);
  r += __shfl_xor(r, 4, 64); r += __shfl_xor(r, 8, 64);
  if (q == 0) y[b * 1024 + o] = lrelu_(r + bias[o]);
}

// ---- MLP 3: 1024 -> 512 ----
__global__ __launch_bounds__(256) void k_mlp3(const float* __restrict__ x,
                        const float* __restrict__ W, const float* __restrict__ bias,
                        float* __restrict__ y){
  int b = blockIdx.x >> 5, og = blockIdx.x & 31;
  int o = og * 16 + (threadIdx.x >> 4);
  int q = threadIdx.x & 15;
  const float4* wr = (const float4*)(W + (size_t)o * 1024);
  const float4* xr = (const float4*)(x + b * 1024);
  float4 a = make_float4(0.f, 0.f, 0.f, 0.f);
  #pragma unroll
  for (int mi = 0; mi < 16; mi++){
    int k4 = q + mi * 16;
    float4 wv = wr[k4], xv = xr[k4];
    a.x = fmaf(xv.x, wv.x, a.x);
    a.y = fmaf(xv.y, wv.y, a.y);
    a.z = fmaf(xv.z, wv.z, a.z);
    a.w = fmaf(xv.w, wv.w, a.w);
  }
  float r = a.x + a.y + a.z + a.w;
  r += __shfl_xor(r, 1, 64); r += __shfl_xor(r, 2, 64);
  r += __shfl_xor(r, 4, 64); r += __shfl_xor(r, 8, 64);
  if (q == 0) y[b * 512 + o] = lrelu_(r + bias[o]);
}

// ---- MLP out: 512 -> 2 ----
__global__ void k_mlp4(const float* __restrict__ f3, const float* __restrict__ Wo,
                       const float* __restrict__ bo, float* __restrict__ out){
  int tid = threadIdx.x;
  int g = tid >> 5, lane = tid & 31;
  int b = g >> 1, o = g & 1;
  const float4* xr = (const float4*)(f3 + b * 512);
  const float4* wr = (const float4*)(Wo + o * 512);
  float4 a = make_float4(0.f, 0.f, 0.f, 0.f);
  #pragma unroll
  for (int mI = 0; mI < 4; mI++){
    int k4 = lane + mI * 32;
    float4 xv = xr[k4], wv = wr[k4];
    a.x = fmaf(xv.x, wv.x, a.x);
    a.y = fmaf(xv.y, wv.y, a.y);
    a.z = fmaf(xv.z, wv.z, a.z);
    a.w = fmaf(xv.w, wv.w, a.w);
  }
  float r = a.x + a.y + a.z + a.w;
  for (int off = 16; off; off >>= 1) r += __shfl_xor(r, off, 64);
  if (lane == 0) out[b * 2 + o] = r + bo[o];
}

extern "C" void kernel_launch(void* const* d_in, const int* in_sizes, int n_in,
                              void* d_out, int out_size, void* d_ws, size_t ws_size,
                              hipStream_t stream) {
  const float* drug  = (const float*)d_in[0];
  const int*   natoms= (const int*)d_in[1];
  const int*   prot  = (const int*)d_in[2];
  const float* emb   = (const float*)d_in[3];
  const float* w1    = (const float*)d_in[4];
  const float* b1    = (const float*)d_in[5];
  const float* w2    = (const float*)d_in[6];
  const float* b2    = (const float*)d_in[7];
  const float* w3    = (const float*)d_in[8];
  const float* b3    = (const float*)d_in[9];
  const float* Wd    = (const float*)d_in[10];
  const float* bd    = (const float*)d_in[11];
  const float* Wp    = (const float*)d_in[12];
  const float* bp    = (const float*)d_in[13];
  const float* Watt  = (const float*)d_in[14];
  const float* batt  = (const float*)d_in[15];
  const float* W1    = (const float*)d_in[16];
  const float* bf1   = (const float*)d_in[17];
  const float* W2    = (const float*)d_in[18];
  const float* bf2   = (const float*)d_in[19];
  const float* W3    = (const float*)d_in[20];
  const float* bf3   = (const float*)d_in[21];
  const float* Wo    = (const float*)d_in[22];
  const float* bo    = (const float*)d_in[23];
  float* out = (float*)d_out;

  float* ws = (float*)d_ws;
  float* h1     = ws;                       // 160000 (dead after k_c2)
  float* cmeanT = ws;                       // 97280 (reuse of h1 region)
  float* f1     = ws + 97280;               // 4096
  float* f2     = ws + 101376;              // 4096
  float* f3     = ws + 105472;              // 2048
  float* h2     = ws + 160000;              // 317440 (post-relu)
  float* pconvA = ws + 477440;              // 627200 (pre-relu partial K-half 0)
  float* dattT  = ws + 1104640;             // 97280
  float* pattT  = ws + 1201920;             // 629760
  float* pmeanT = ws + 1831680;             // 629760
  unsigned* enc = (unsigned*)(ws + 2461440);// 1280 u32
  float* projG  = ws + 2461760;             // 4186
  float* pconvB = ws + 2466048;             // 627200 (pre-relu partial K-half 1)

  k_proj  <<<17, 256, 0, stream>>>(emb, w1, projG);
  k_conv1 <<<BB * 80, 256, 0, stream>>>(prot, projG, b1, h1);
  k_c2    <<<620, 128, 0, stream>>>(h1, w2, b2, h2);
  k_c3    <<<640, 256, 0, stream>>>(h2, w3, b3, pconvA, pconvB);
  k_dpatt <<<800, 128, 0, stream>>>(drug, natoms, Wd, bd, dattT, enc,
                                    pconvA, pconvB, prot, Wp, bp, pattT);
  k_means <<<BB * NC3, 256, 0, stream>>>(dattT, pattT, cmeanT, pmeanT);
  k_atte  <<<800, 128, 0, stream>>>(cmeanT, pmeanT, Watt, batt, drug,
                                    pconvA, pconvB, enc);
  k_mlp1  <<<256, 256, 0, stream>>>(enc, W1, bf1, f1);
  k_mlp2  <<<256, 256, 0, stream>>>(f1, W2, bf2, f2);
  k_mlp3  <<<128, 256, 0, stream>>>(f2, W3, bf3, f3);
  k_mlp4  <<<1, 256, 0, stream>>>(f3, Wo, bo, out);
}

// Round 9
// 147.542 us; speedup vs baseline: 1.2702x; 1.2702x over previous
//
#include <hip/hip_runtime.h>
#include <math.h>

#define BB 4
#define DL 150
#define PL 1000
#define CD 64
#define NC1 40
#define NC2 80
#define NC3 160
#define L1O 997
#define L2O 990
#define L3O 979
#define L1P 1000
#define L2P 992
#define L3P 980
#define DLP 152
#define PLP 984
#define NINF (-1e30f)

typedef __attribute__((ext_vector_type(8))) short bf16x8;
typedef __attribute__((ext_vector_type(4))) float f32x4;

__device__ __forceinline__ float relu_(float x){ return fmaxf(x, 0.f); }
__device__ __forceinline__ float lrelu_(float x){ return x > 0.f ? x : 0.01f * x; }

__device__ __forceinline__ unsigned fenc(float x){
  unsigned u = __float_as_uint(x);
  return (u & 0x80000000u) ? ~u : (u | 0x80000000u);
}
__device__ __forceinline__ float fdec(unsigned u){
  return __uint_as_float((u & 0x80000000u) ? (u & 0x7fffffffu) : ~u);
}
__device__ __forceinline__ float4 relu4_(float4 v){
  v.x = fmaxf(v.x, 0.f); v.y = fmaxf(v.y, 0.f);
  v.z = fmaxf(v.z, 0.f); v.w = fmaxf(v.w, 0.f);
  return v;
}
__device__ __forceinline__ unsigned short bf16_(float x){
  unsigned u = __float_as_uint(x);
  unsigned r = (u + 0x7FFFu + ((u >> 16) & 1u)) >> 16;
  return (unsigned short)r;
}

// ---- proj table ----
__global__ void k_proj(const float* __restrict__ emb, const float* __restrict__ w1,
                       float* __restrict__ projG){
  int e = blockIdx.x * 256 + threadIdx.x;
  if (e >= 26 * 160) return;
  int tok = e / 160, rem = e % 160, k = rem / 40, co = rem % 40;
  float a = 0.f;
  const float* er = emb + tok * CD;
  const float* wr = w1 + co * (CD * 4) + k;
  #pragma unroll 8
  for (int ci = 0; ci < CD; ci++) a = fmaf(er[ci], wr[ci * 4], a);
  projG[tok * 161 + k * 40 + co] = a;
}

// ---- w3 reorder + pad + bf16 cast: w3r[kk][co][ci96] ----
__global__ __launch_bounds__(256) void k_w3r(const float* __restrict__ w3,
                        unsigned short* __restrict__ w3r){
  int e = blockIdx.x * 256 + threadIdx.x;
  if (e >= 12 * 160 * 96) return;
  int kk = e / (160 * 96); int r = e % (160 * 96);
  int co = r / 96, ci = r % 96;
  float v = (ci < NC2) ? w3[(size_t)co * 960 + ci * 12 + kk] : 0.f;
  w3r[e] = bf16_(v);
}

// ---- conv1 apply (writes relu'd h1) ----
__global__ __launch_bounds__(256) void k_conv1(const int* __restrict__ prot,
                        const float* __restrict__ projG, const float* __restrict__ b1,
                        float* __restrict__ h1){
  __shared__ float sp[26 * 161];
  int b = blockIdx.x / 80;
  int t = (blockIdx.x % 80) * 256 + threadIdx.x;
  for (int k = threadIdx.x; k < 26 * 161; k += 256) sp[k] = projG[k];
  __syncthreads();
  int p = t & 1023, co2 = t >> 10;
  if (p >= L1O) return;
  const int* pr = prot + b * PL + p;
  int t0 = pr[0], t1 = pr[1], t2 = pr[2], t3 = pr[3];
  #pragma unroll
  for (int c = 0; c < 2; c++){
    int co = co2 * 2 + c;
    float a = b1[co] + sp[t0 * 161 + co] + sp[t1 * 161 + 40 + co]
            + sp[t2 * 161 + 80 + co] + sp[t3 * 161 + 120 + co];
    h1[(size_t)(b * NC1 + co) * L1P + p] = relu_(a);
  }
}

// ---- conv2: LDS whole-K tiled ----
#define C2XW 44
#define C2WP 324
__global__ __launch_bounds__(128) void k_c2(const float* __restrict__ h1,
                        const float* __restrict__ w, const float* __restrict__ bias,
                        float* __restrict__ h2){
  __shared__ float xs[NC1 * C2XW];
  __shared__ float wl[16 * C2WP];
  int blk = blockIdx.x;
  int pt = blk % 31; int t = blk / 31;
  int cog = t % 5; int b = t / 5;
  int co0 = cog * 16, pblk = pt * 32;
  int tid = threadIdx.x;
  const float* xb = h1 + (size_t)(b * NC1) * L1P + pblk;
  for (int i = tid; i < 440; i += 128){
    int r = i / 11, c = i % 11;
    *(float4*)(&xs[r * C2XW + c * 4]) = *(const float4*)(xb + (size_t)r * L1P + c * 4);
  }
  for (int i = tid; i < 1280; i += 128){
    int cc = i / 80, c = i % 80;
    *(float4*)(&wl[cc * C2WP + c * 4]) =
        *(const float4*)(w + (size_t)(co0 + cc) * 320 + c * 4);
  }
  __syncthreads();
  int co_l = tid >> 3, pg = tid & 7, p0 = pg * 4;
  float acc[4] = {0,0,0,0};
  const float* wc = &wl[co_l * C2WP];
  #pragma unroll 2
  for (int ci = 0; ci < NC1; ci++){
    const float* xrow = &xs[ci * C2XW + p0];
    float xv[12];
    *(float4*)(&xv[0]) = *(const float4*)(xrow);
    *(float4*)(&xv[4]) = *(const float4*)(xrow + 4);
    *(float4*)(&xv[8]) = *(const float4*)(xrow + 8);
    float wk[8];
    *(float4*)(&wk[0]) = *(const float4*)(wc + ci * 8);
    *(float4*)(&wk[4]) = *(const float4*)(wc + ci * 8 + 4);
    #pragma unroll
    for (int k = 0; k < 8; k++){
      #pragma unroll
      for (int pp = 0; pp < 4; pp++)
        acc[pp] = fmaf(xv[pp + k], wk[k], acc[pp]);
    }
  }
  int co = co0 + co_l;
  float bv = bias[co];
  int pbase = pblk + p0;
  float* yr = h2 + (size_t)(b * NC2 + co) * L2P + pbase;
  if (pbase + 3 < L2O){
    float4 o; o.x = relu_(acc[0] + bv); o.y = relu_(acc[1] + bv);
    o.z = relu_(acc[2] + bv); o.w = relu_(acc[3] + bv);
    *(float4*)yr = o;
  } else {
    #pragma unroll
    for (int pp = 0; pp < 4; pp++)
      if (pbase + pp < L2O) yr[pp] = relu_(acc[pp] + bv);
  }
}

// ---- transpose + bf16 cast: h2[b][ci][p] -> h2bT[b][p 992][ci 96] ----
__global__ __launch_bounds__(256) void k_t2(const float* __restrict__ h2,
                        unsigned short* __restrict__ h2bT){
  __shared__ float tile[32][33];
  int blk = blockIdx.x;
  int pt = blk % 31; int t = blk / 31;
  int cit = t % 3; int b = t / 3;
  int ci0 = cit * 32, p0 = pt * 32;
  int r = threadIdx.x >> 5, c = threadIdx.x & 31;
  #pragma unroll
  for (int rr = 0; rr < 4; rr++){
    int ci = ci0 + r * 4 + rr;
    float v = (ci < NC2) ? h2[(size_t)(b * NC2 + ci) * L2P + p0 + c] : 0.f;
    tile[r * 4 + rr][c] = v;
  }
  __syncthreads();
  #pragma unroll
  for (int rr = 0; rr < 4; rr++){
    int prow = p0 + r * 4 + rr;
    h2bT[((size_t)b * 992 + prow) * 96 + ci0 + c] = bf16_(tile[c][r * 4 + rr]);
  }
}

// ---- conv3 via MFMA bf16: grid 640 = b(4) x cog(10,16co) x pt(16,64p); 4 waves ----
__global__ __launch_bounds__(256) void k_c3m(const unsigned short* __restrict__ h2bT,
                        const unsigned short* __restrict__ w3r,
                        const float* __restrict__ bias, float* __restrict__ pconv){
  int blk = blockIdx.x;
  int pt = blk % 16; int t = blk / 16;
  int cog = t % 10; int b = t / 10;
  int co0 = cog * 16;
  int wave = threadIdx.x >> 6, lane = threadIdx.x & 63;
  int col = lane & 15, g = lane >> 4;
  int p0 = pt * 64 + wave * 16;
  f32x4 acc = {0.f, 0.f, 0.f, 0.f};
  const unsigned short* wbase = w3r + (size_t)(co0 + col) * 96 + g * 8;
  const unsigned short* xbase = h2bT + (size_t)b * 992 * 96 + g * 8;
  int prow = p0 + col;
  for (int kk = 0; kk < 12; kk++){
    int rp = prow + kk; if (rp > 991) rp = 991;
    const unsigned short* xr = xbase + (size_t)rp * 96;
    const unsigned short* wr = wbase + (size_t)kk * (160 * 96);
    #pragma unroll
    for (int ks = 0; ks < 3; ks++){
      bf16x8 av = *(const bf16x8*)(wr + ks * 32);
      bf16x8 bv = *(const bf16x8*)(xr + ks * 32);
      acc = __builtin_amdgcn_mfma_f32_16x16x32_bf16(av, bv, acc, 0, 0, 0);
    }
  }
  if (p0 >= L3O) return;
  int p = p0 + col;
  if (p < L3O){
    #pragma unroll
    for (int r = 0; r < 4; r++){
      int co = co0 + g * 4 + r;
      pconv[(size_t)(b * NC3 + co) * L3P + p] = acc[r] + bias[co];
    }
  }
}

// ---- fused: blocks 0..159 drug-att (+enc init); blocks 160..799 protein-att ----
__global__ __launch_bounds__(128) void k_dpatt(const float* __restrict__ drug,
                        const int* __restrict__ natoms,
                        const float* __restrict__ Wd, const float* __restrict__ bd,
                        float* __restrict__ dattT, unsigned* __restrict__ enc,
                        const float* __restrict__ pconv,
                        const int* __restrict__ prot,
                        const float* __restrict__ Wp, const float* __restrict__ bp,
                        float* __restrict__ pattT){
  __shared__ float xs[160 * 68];
  __shared__ float wl[16 * 164];
  int blk = blockIdx.x;
  int tid = threadIdx.x;
  if (blk < 160){
    if (blk == 0){
      for (int k = tid; k < 2 * BB * NC3; k += 128) enc[k] = 0u;
    }
    int b = blk / 40, c0 = (blk % 40) * 4;
    for (int i = tid; i < DL; i += 128){
      const float4* xr = (const float4*)(drug + ((size_t)b * DL + i) * NC3);
      float4 a[4];
      #pragma unroll
      for (int cc = 0; cc < 4; cc++) a[cc] = make_float4(0.f, 0.f, 0.f, 0.f);
      for (int k4 = 0; k4 < 40; k4++){
        float4 xv = xr[k4];
        #pragma unroll
        for (int cc = 0; cc < 4; cc++){
          float4 wv = ((const float4*)(Wd + (size_t)(c0 + cc) * NC3))[k4];
          a[cc].x = fmaf(xv.x, wv.x, a[cc].x);
          a[cc].y = fmaf(xv.y, wv.y, a[cc].y);
          a[cc].z = fmaf(xv.z, wv.z, a[cc].z);
          a[cc].w = fmaf(xv.w, wv.w, a[cc].w);
        }
      }
      bool act = i < natoms[b];
      #pragma unroll
      for (int cc = 0; cc < 4; cc++){
        float r = act ? (a[cc].x + a[cc].y + a[cc].z + a[cc].w + bd[c0 + cc]) : 0.f;
        dattT[(size_t)(b * NC3 + c0 + cc) * DLP + i] = r;
      }
    }
    return;
  }
  int q = blk - 160;
  int jt = q & 15; int t = q >> 4;
  int cog = t % 10; int b = t / 10;
  int co0 = cog * 16, j0t = jt * 64;
  const float* xb = pconv + (size_t)(b * NC3) * L3P + j0t;
  for (int i = tid; i < 2720; i += 128){
    int r = i / 17, c = i % 17;
    float4 v = *(const float4*)(xb + (size_t)r * L3P + c * 4);
    *(float4*)(&xs[r * 68 + c * 4]) = relu4_(v);
  }
  for (int i = tid; i < 640; i += 128){
    int cc = i / 40, c = i % 40;
    *(float4*)(&wl[cc * 164 + c * 4]) =
        *(const float4*)(Wp + (size_t)(co0 + cc) * NC3 + c * 4);
  }
  __syncthreads();
  int cp = tid >> 4, jg = tid & 15;
  int j0 = jg * 4;
  float acc0[4] = {0,0,0,0}, acc1[4] = {0,0,0,0};
  const float* xcol = xs + j0;
  const float* w0r = wl + (cp * 2) * 164;
  const float* w1r = wl + (cp * 2 + 1) * 164;
  #pragma unroll 2
  for (int k4 = 0; k4 < 40; k4++){
    float4 wa = *(const float4*)(w0r + k4 * 4);
    float4 wb = *(const float4*)(w1r + k4 * 4);
    float4 x0 = *(const float4*)(xcol + (k4 * 4 + 0) * 68);
    float4 x1 = *(const float4*)(xcol + (k4 * 4 + 1) * 68);
    float4 x2 = *(const float4*)(xcol + (k4 * 4 + 2) * 68);
    float4 x3 = *(const float4*)(xcol + (k4 * 4 + 3) * 68);
    acc0[0] = fmaf(x0.x, wa.x, fmaf(x1.x, wa.y, fmaf(x2.x, wa.z, fmaf(x3.x, wa.w, acc0[0]))));
    acc0[1] = fmaf(x0.y, wa.x, fmaf(x1.y, wa.y, fmaf(x2.y, wa.z, fmaf(x3.y, wa.w, acc0[1]))));
    acc0[2] = fmaf(x0.z, wa.x, fmaf(x1.z, wa.y, fmaf(x2.z, wa.z, fmaf(x3.z, wa.w, acc0[2]))));
    acc0[3] = fmaf(x0.w, wa.x, fmaf(x1.w, wa.y, fmaf(x2.w, wa.z, fmaf(x3.w, wa.w, acc0[3]))));
    acc1[0] = fmaf(x0.x, wb.x, fmaf(x1.x, wb.y, fmaf(x2.x, wb.z, fmaf(x3.x, wb.w, acc1[0]))));
    acc1[1] = fmaf(x0.y, wb.x, fmaf(x1.y, wb.y, fmaf(x2.y, wb.z, fmaf(x3.y, wb.w, acc1[1]))));
    acc1[2] = fmaf(x0.z, wb.x, fmaf(x1.z, wb.y, fmaf(x2.z, wb.z, fmaf(x3.z, wb.w, acc1[2]))));
    acc1[3] = fmaf(x0.w, wb.x, fmaf(x1.w, wb.y, fmaf(x2.w, wb.z, fmaf(x3.w, wb.w, acc1[3]))));
  }
  int coA = co0 + cp * 2, coB = coA + 1;
  float bA = bp[coA], bB = bp[coB];
  int jb = j0t + j0;
  const int* pr = prot + b * PL;
  #pragma unroll
  for (int qq = 0; qq < 4; qq++){
    int j = jb + qq;
    if (j < L3O){
      bool act = pr[j] > 0;
      pattT[(size_t)(b * NC3 + coA) * PLP + j] = act ? (acc0[qq] + bA) : 0.f;
      pattT[(size_t)(b * NC3 + coB) * PLP + j] = act ? (acc1[qq] + bB) : 0.f;
    }
  }
}

// ---- means, rebalanced ----
__global__ __launch_bounds__(256) void k_means(const float* __restrict__ dattT,
                        const float* __restrict__ pattT,
                        float* __restrict__ cmeanT, float* __restrict__ pmeanT){
  __shared__ float sda[DLP];
  __shared__ float spa[PLP];
  __shared__ float scm[4][DLP];
  int b = blockIdx.x / NC3, c = blockIdx.x % NC3;
  int tid = threadIdx.x;
  const float4* dr = (const float4*)(dattT + (size_t)(b * NC3 + c) * DLP);
  const float4* pr = (const float4*)(pattT + (size_t)(b * NC3 + c) * PLP);
  if (tid < DLP / 4) *(float4*)(&sda[tid * 4]) = dr[tid];
  if (tid < PLP / 4) *(float4*)(&spa[tid * 4]) = pr[tid];
  __syncthreads();
  for (int t = tid; t < 600; t += 256){
    int i = t >> 2, qq = t & 3;
    int js = qq * 245, je = (qq == 3) ? L3O : js + 245;
    float v = sda[i];
    float s0 = 0.f, s1 = 0.f;
    int j = js;
    for (; j + 1 < je; j += 2){
      s0 += relu_(v + spa[j]);
      s1 += relu_(v + spa[j + 1]);
    }
    if (j < je) s0 += relu_(v + spa[j]);
    scm[qq][i] = s0 + s1;
  }
  for (int j = tid; j < L3O; j += 256){
    float v = spa[j];
    float s0 = 0.f, s1 = 0.f;
    #pragma unroll 2
    for (int i = 0; i < DL; i += 2){
      s0 += relu_(v + sda[i]);
      s1 += relu_(v + sda[i + 1]);
    }
    pmeanT[(size_t)(b * NC3 + c) * PLP + j] = (s0 + s1) * (1.f / DL);
  }
  __syncthreads();
  if (tid < DL){
    float s = scm[0][tid] + scm[1][tid] + scm[2][tid] + scm[3][tid];
    cmeanT[(size_t)(b * NC3 + c) * DLP + tid] = s * (1.f / L3O);
  }
}

// ---- fused gates: blocks 0..159 compound; 160..799 protein ----
__global__ __launch_bounds__(128) void k_atte(const float* __restrict__ cmeanT,
                        const float* __restrict__ pmeanT,
                        const float* __restrict__ Watt, const float* __restrict__ batt,
                        const float* __restrict__ drug,
                        const float* __restrict__ pconv, unsigned* __restrict__ enc){
  __shared__ float xs[160 * 68];
  __shared__ float wl[16 * 164];
  int blk = blockIdx.x;
  int tid = threadIdx.x;
  if (blk < 160){
    __shared__ float sred[2][4];
    int b = blk / 40, c0 = (blk % 40) * 4;
    float m[4];
    #pragma unroll
    for (int cc = 0; cc < 4; cc++) m[cc] = NINF;
    for (int i = tid; i < DL; i += 128){
      float acc[4];
      #pragma unroll
      for (int cc = 0; cc < 4; cc++) acc[cc] = batt[c0 + cc];
      const float* xc = cmeanT + (size_t)b * NC3 * DLP + i;
      const float* wr = Watt + (size_t)c0 * NC3;
      for (int cb = 0; cb < NC3; cb += 32){
        float xv[32];
        #pragma unroll
        for (int u = 0; u < 32; u++) xv[u] = xc[(size_t)(cb + u) * DLP];
        #pragma unroll
        for (int u = 0; u < 32; u++){
          #pragma unroll
          for (int cc = 0; cc < 4; cc++)
            acc[cc] = fmaf(xv[u], wr[(size_t)cc * NC3 + cb + u], acc[cc]);
        }
      }
      const float* gr = drug + ((size_t)b * DL + i) * NC3 + c0;
      #pragma unroll
      for (int cc = 0; cc < 4; cc++){
        float atte = 1.f / (1.f + expf(-acc[cc]));
        m[cc] = fmaxf(m[cc], gr[cc] * (0.5f + atte));
      }
    }
    int wave = tid >> 6, lane = tid & 63;
    #pragma unroll
    for (int cc = 0; cc < 4; cc++){
      float v = m[cc];
      for (int off = 1; off < 64; off <<= 1) v = fmaxf(v, __shfl_xor(v, off, 64));
      if (lane == 0) sred[wave][cc] = v;
    }
    __syncthreads();
    if (tid < 4){
      float v = fmaxf(sred[0][tid], sred[1][tid]);
      atomicMax(&enc[b * NC3 + c0 + tid], fenc(v));
    }
    return;
  }
  int q = blk - 160;
  int jt = q & 15; int t = q >> 4;
  int cog = t % 10; int b = t / 10;
  int co0 = cog * 16, j0t = jt * 64;
  const float* xb = pmeanT + (size_t)(b * NC3) * PLP + j0t;
  for (int i = tid; i < 2720; i += 128){
    int r = i / 17, c = i % 17;
    *(float4*)(&xs[r * 68 + c * 4]) = *(const float4*)(xb + (size_t)r * PLP + c * 4);
  }
  for (int i = tid; i < 640; i += 128){
    int cc = i / 40, c = i % 40;
    *(float4*)(&wl[cc * 164 + c * 4]) =
        *(const float4*)(Watt + (size_t)(co0 + cc) * NC3 + c * 4);
  }
  __syncthreads();
  int cp = tid >> 4, jg = tid & 15;
  int j0 = jg * 4;
  float acc0[4] = {0,0,0,0}, acc1[4] = {0,0,0,0};
  const float* xcol = xs + j0;
  const float* w0r = wl + (cp * 2) * 164;
  const float* w1r = wl + (cp * 2 + 1) * 164;
  #pragma unroll 2
  for (int k4 = 0; k4 < 40; k4++){
    float4 wa = *(const float4*)(w0r + k4 * 4);
    float4 wb = *(const float4*)(w1r + k4 * 4);
    float4 x0 = *(const float4*)(xcol + (k4 * 4 + 0) * 68);
    float4 x1 = *(const float4*)(xcol + (k4 * 4 + 1) * 68);
    float4 x2 = *(const float4*)(xcol + (k4 * 4 + 2) * 68);
    float4 x3 = *(const float4*)(xcol + (k4 * 4 + 3) * 68);
    acc0[0] = fmaf(x0.x, wa.x, fmaf(x1.x, wa.y, fmaf(x2.x, wa.z, fmaf(x3.x, wa.w, acc0[0]))));
    acc0[1] = fmaf(x0.y, wa.x, fmaf(x1.y, wa.y, fmaf(x2.y, wa.z, fmaf(x3.y, wa.w, acc0[1]))));
    acc0[2] = fmaf(x0.z, wa.x, fmaf(x1.z, wa.y, fmaf(x2.z, wa.z, fmaf(x3.z, wa.w, acc0[2]))));
    acc0[3] = fmaf(x0.w, wa.x, fmaf(x1.w, wa.y, fmaf(x2.w, wa.z, fmaf(x3.w, wa.w, acc0[3]))));
    acc1[0] = fmaf(x0.x, wb.x, fmaf(x1.x, wb.y, fmaf(x2.x, wb.z, fmaf(x3.x, wb.w, acc1[0]))));
    acc1[1] = fmaf(x0.y, wb.x, fmaf(x1.y, wb.y, fmaf(x2.y, wb.z, fmaf(x3.y, wb.w, acc1[1]))));
    acc1[2] = fmaf(x0.z, wb.x, fmaf(x1.z, wb.y, fmaf(x2.z, wb.z, fmaf(x3.z, wb.w, acc1[2]))));
    acc1[3] = fmaf(x0.w, wb.x, fmaf(x1.w, wb.y, fmaf(x2.w, wb.z, fmaf(x3.w, wb.w, acc1[3]))));
  }
  int coA = co0 + cp * 2, coB = coA + 1;
  float bA = batt[coA], bB = batt[coB];
  int jb = j0t + j0;
  float mA = NINF, mB = NINF;
  if (jb < L3P){
    const float* rA = pconv + (size_t)(b * NC3 + coA) * L3P + jb;
    const float* rB = pconv + (size_t)(b * NC3 + coB) * L3P + jb;
    float4 a0 = *(const float4*)rA;
    float4 a1 = *(const float4*)rB;
    float pAr[4] = {a0.x, a0.y, a0.z, a0.w};
    float pBr[4] = {a1.x, a1.y, a1.z, a1.w};
    #pragma unroll
    for (int qq = 0; qq < 4; qq++){
      int j = jb + qq;
      if (j < L3O){
        float gA = 1.f / (1.f + expf(-(acc0[qq] + bA)));
        float gB = 1.f / (1.f + expf(-(acc1[qq] + bB)));
        mA = fmaxf(mA, relu_(pAr[qq]) * (0.5f + gA));
        mB = fmaxf(mB, relu_(pBr[qq]) * (0.5f + gB));
      }
    }
  }
  #pragma unroll
  for (int off = 1; off < 16; off <<= 1){
    mA = fmaxf(mA, __shfl_xor(mA, off, 64));
    mB = fmaxf(mB, __shfl_xor(mB, off, 64));
  }
  if (jg == 0){
    atomicMax(&enc[BB * NC3 + b * NC3 + coA], fenc(mA));
    atomicMax(&enc[BB * NC3 + b * NC3 + coB], fenc(mB));
  }
}

// ---- MLP 1: 320 -> 1024 ----
__global__ __launch_bounds__(256) void k_mlp1(const unsigned* __restrict__ enc,
                        const float* __restrict__ W1, const float* __restrict__ bf1,
                        float* __restrict__ f1){
  int b = blockIdx.x >> 6, og = blockIdx.x & 63;
  int o = og * 16 + (threadIdx.x >> 4);
  int q = threadIdx.x & 15;
  const float4* wr = (const float4*)(W1 + (size_t)o * 320);
  float4 a = make_float4(0.f, 0.f, 0.f, 0.f);
  #pragma unroll
  for (int mi = 0; mi < 5; mi++){
    int k4 = q + mi * 16;
    int k = k4 * 4;
    const unsigned* e = (k < 160) ? (enc + b * NC3 + k)
                                  : (enc + BB * NC3 + b * NC3 + (k - 160));
    float4 wv = wr[k4];
    a.x = fmaf(fdec(e[0]), wv.x, a.x);
    a.y = fmaf(fdec(e[1]), wv.y, a.y);
    a.z = fmaf(fdec(e[2]), wv.z, a.z);
    a.w = fmaf(fdec(e[3]), wv.w, a.w);
  }
  float r = a.x + a.y + a.z + a.w;
  r += __shfl_xor(r, 1, 64); r += __shfl_xor(r, 2, 64);
  r += __shfl_xor(r, 4, 64); r += __shfl_xor(r, 8, 64);
  if (q == 0) f1[b * 1024 + o] = lrelu_(r + bf1[o]);
}

// ---- MLP 2: 1024 -> 1024 ----
__global__ __launch_bounds__(256) void k_mlp2(const float* __restrict__ x,
                        const float* __restrict__ W, const float* __restrict__ bias,
                        float* __restrict__ y){
  int b = blockIdx.x >> 6, og = blockIdx.x & 63;
  int o = og * 16 + (threadIdx.x >> 4);
  int q = threadIdx.x & 15;
  const float4* wr = (const float4*)(W + (size_t)o * 1024);
  const float4* xr = (const float4*)(x + b * 1024);
  float4 a = make_float4(0.f, 0.f, 0.f, 0.f);
  #pragma unroll
  for (int mi = 0; mi < 16; mi++){
    int k4 = q + mi * 16;
    float4 wv = wr[k4], xv = xr[k4];
    a.x = fmaf(xv.x, wv.x, a.x);
    a.y = fmaf(xv.y, wv.y, a.y);
    a.z = fmaf(xv.z, wv.z, a.z);
    a.w = fmaf(xv.w, wv.w, a.w);
  }
  float r = a.x + a.y + a.z + a.w;
  r += __shfl_xor(r, 1, 64); r += __shfl_xor(r, 2, 64);
  r += __shfl_xor(r, 4, 64); r += __shfl_xor(r, 8, 64);
  if (q == 0) y[b * 1024 + o] = lrelu_(r + bias[o]);
}

// ---- MLP 3: 1024 -> 512 ----
__global__ __launch_bounds__(256) void k_mlp3(const float* __restrict__ x,
                        const float* __restrict__ W, const float* __restrict__ bias,
                        float* __restrict__ y){
  int b = blockIdx.x >> 5, og = blockIdx.x & 31;
  int o = og * 16 + (threadIdx.x >> 4);
  int q = threadIdx.x & 15;
  const float4* wr = (const float4*)(W + (size_t)o * 1024);
  const float4* xr = (const float4*)(x + b * 1024);
  float4 a = make_float4(0.f, 0.f, 0.f, 0.f);
  #pragma unroll
  for (int mi = 0; mi < 16; mi++){
    int k4 = q + mi * 16;
    float4 wv = wr[k4], xv = xr[k4];
    a.x = fmaf(xv.x, wv.x, a.x);
    a.y = fmaf(xv.y, wv.y, a.y);
    a.z = fmaf(xv.z, wv.z, a.z);
    a.w = fmaf(xv.w, wv.w, a.w);
  }
  float r = a.x + a.y + a.z + a.w;
  r += __shfl_xor(r, 1, 64); r += __shfl_xor(r, 2, 64);
  r += __shfl_xor(r, 4, 64); r += __shfl_xor(r, 8, 64);
  if (q == 0) y[b * 512 + o] = lrelu_(r + bias[o]);
}

// ---- MLP out: 512 -> 2 ----
__global__ void k_mlp4(const float* __restrict__ f3, const float* __restrict__ Wo,
                       const float* __restrict__ bo, float* __restrict__ out){
  int tid = threadIdx.x;
  int g = tid >> 5, lane = tid & 31;
  int b = g >> 1, o = g & 1;
  const float4* xr = (const float4*)(f3 + b * 512);
  const float4* wr = (const float4*)(Wo + o * 512);
  float4 a = make_float4(0.f, 0.f, 0.f, 0.f);
  #pragma unroll
  for (int mI = 0; mI < 4; mI++){
    int k4 = lane + mI * 32;
    float4 xv = xr[k4], wv = wr[k4];
    a.x = fmaf(xv.x, wv.x, a.x);
    a.y = fmaf(xv.y, wv.y, a.y);
    a.z = fmaf(xv.z, wv.z, a.z);
    a.w = fmaf(xv.w, wv.w, a.w);
  }
  float r = a.x + a.y + a.z + a.w;
  for (int off = 16; off; off >>= 1) r += __shfl_xor(r, off, 64);
  if (lane == 0) out[b * 2 + o] = r + bo[o];
}

extern "C" void kernel_launch(void* const* d_in, const int* in_sizes, int n_in,
                              void* d_out, int out_size, void* d_ws, size_t ws_size,
                              hipStream_t stream) {
  const float* drug  = (const float*)d_in[0];
  const int*   natoms= (const int*)d_in[1];
  const int*   prot  = (const int*)d_in[2];
  const float* emb   = (const float*)d_in[3];
  const float* w1    = (const float*)d_in[4];
  const float* b1    = (const float*)d_in[5];
  const float* w2    = (const float*)d_in[6];
  const float* b2    = (const float*)d_in[7];
  const float* w3    = (const float*)d_in[8];
  const float* b3    = (const float*)d_in[9];
  const float* Wd    = (const float*)d_in[10];
  const float* bd    = (const float*)d_in[11];
  const float* Wp    = (const float*)d_in[12];
  const float* bp    = (const float*)d_in[13];
  const float* Watt  = (const float*)d_in[14];
  const float* batt  = (const float*)d_in[15];
  const float* W1    = (const float*)d_in[16];
  const float* bf1   = (const float*)d_in[17];
  const float* W2    = (const float*)d_in[18];
  const float* bf2   = (const float*)d_in[19];
  const float* W3    = (const float*)d_in[20];
  const float* bf3   = (const float*)d_in[21];
  const float* Wo    = (const float*)d_in[22];
  const float* bo    = (const float*)d_in[23];
  float* out = (float*)d_out;

  float* ws = (float*)d_ws;
  float* h1     = ws;                       // 160000 (dead after k_c2)
  float* cmeanT = ws;                       // 97280 (reuse of h1 region)
  float* f1     = ws + 97280;               // 4096
  float* f2     = ws + 101376;              // 4096
  float* f3     = ws + 105472;              // 2048
  float* h2     = ws + 160000;              // 317440 (post-relu f32)
  float* pconv  = ws + 477440;              // 627200 (post-bias pre-relu f32)
  float* dattT  = ws + 1104640;             // 97280
  float* pattT  = ws + 1201920;             // 629760
  float* pmeanT = ws + 1831680;             // 629760
  unsigned* enc = (unsigned*)(ws + 2461440);// 1280 u32
  float* projG  = ws + 2461760;             // 4186
  unsigned short* h2bT = (unsigned short*)(ws + 2466048); // 380928 bf16
  unsigned short* w3r  = (unsigned short*)(ws + 2656512); // 184320 bf16

  k_proj  <<<17, 256, 0, stream>>>(emb, w1, projG);
  k_w3r   <<<720, 256, 0, stream>>>(w3, w3r);
  k_conv1 <<<BB * 80, 256, 0, stream>>>(prot, projG, b1, h1);
  k_c2    <<<620, 128, 0, stream>>>(h1, w2, b2, h2);
  k_t2    <<<372, 256, 0, stream>>>(h2, h2bT);
  k_c3m   <<<640, 256, 0, stream>>>(h2bT, w3r, b3, pconv);
  k_dpatt <<<800, 128, 0, stream>>>(drug, natoms, Wd, bd, dattT, enc,
                                    pconv, prot, Wp, bp, pattT);
  k_means <<<BB * NC3, 256, 0, stream>>>(dattT, pattT, cmeanT, pmeanT);
  k_atte  <<<800, 128, 0, stream>>>(cmeanT, pmeanT, Watt, batt, drug,
                                    pconv, enc);
  k_mlp1  <<<256, 256, 0, stream>>>(enc, W1, bf1, f1);
  k_mlp2  <<<256, 256, 0, stream>>>(f1, W2, bf2, f2);
  k_mlp3  <<<128, 256, 0, stream>>>(f2, W3, bf3, f3);
  k_mlp4  <<<1, 256, 0, stream>>>(f3, Wo, bo, out);
}

// Round 10
// 131.108 us; speedup vs baseline: 1.4294x; 1.1253x over previous
//
#include <hip/hip_runtime.h>
#include <math.h>

#define BB 4
#define DL 150
#define PL 1000
#define CD 64
#define NC1 40
#define NC2 80
#define NC3 160
#define L1O 997
#define L2O 990
#define L3O 979
#define L1P 1000
#define L2P 992
#define L3P 980
#define DLP 152
#define PLP 984
#define NINF (-1e30f)

typedef __attribute__((ext_vector_type(8))) short bf16x8;
typedef __attribute__((ext_vector_type(4))) float f32x4;

__device__ __forceinline__ float relu_(float x){ return fmaxf(x, 0.f); }
__device__ __forceinline__ float lrelu_(float x){ return x > 0.f ? x : 0.01f * x; }

__device__ __forceinline__ unsigned fenc(float x){
  unsigned u = __float_as_uint(x);
  return (u & 0x80000000u) ? ~u : (u | 0x80000000u);
}
__device__ __forceinline__ float fdec(unsigned u){
  return __uint_as_float((u & 0x80000000u) ? (u & 0x7fffffffu) : ~u);
}
__device__ __forceinline__ float4 relu4_(float4 v){
  v.x = fmaxf(v.x, 0.f); v.y = fmaxf(v.y, 0.f);
  v.z = fmaxf(v.z, 0.f); v.w = fmaxf(v.w, 0.f);
  return v;
}
__device__ __forceinline__ unsigned short bf16_(float x){
  unsigned u = __float_as_uint(x);
  unsigned r = (u + 0x7FFFu + ((u >> 16) & 1u)) >> 16;
  return (unsigned short)r;
}

// ---- fused: blocks 0..16 proj table; blocks 17..736 w3 reorder ----
__global__ __launch_bounds__(256) void k_prep(const float* __restrict__ emb,
                       const float* __restrict__ w1, float* __restrict__ projG,
                       const float* __restrict__ w3, unsigned short* __restrict__ w3r){
  int blk = blockIdx.x;
  if (blk < 17){
    int e = blk * 256 + threadIdx.x;
    if (e >= 26 * 160) return;
    int tok = e / 160, rem = e % 160, k = rem / 40, co = rem % 40;
    float a = 0.f;
    const float* er = emb + tok * CD;
    const float* wr = w1 + co * (CD * 4) + k;
    #pragma unroll 8
    for (int ci = 0; ci < CD; ci++) a = fmaf(er[ci], wr[ci * 4], a);
    projG[tok * 161 + k * 40 + co] = a;
    return;
  }
  int e = (blk - 17) * 256 + threadIdx.x;
  if (e >= 12 * 160 * 96) return;
  int kk = e / (160 * 96); int r = e % (160 * 96);
  int co = r / 96, ci = r % 96;
  float v = (ci < NC2) ? w3[(size_t)co * 960 + ci * 12 + kk] : 0.f;
  w3r[e] = bf16_(v);
}

// ---- conv1 apply (writes relu'd h1) ----
__global__ __launch_bounds__(256) void k_conv1(const int* __restrict__ prot,
                        const float* __restrict__ projG, const float* __restrict__ b1,
                        float* __restrict__ h1){
  __shared__ float sp[26 * 161];
  int b = blockIdx.x / 80;
  int t = (blockIdx.x % 80) * 256 + threadIdx.x;
  for (int k = threadIdx.x; k < 26 * 161; k += 256) sp[k] = projG[k];
  __syncthreads();
  int p = t & 1023, co2 = t >> 10;
  if (p >= L1O) return;
  const int* pr = prot + b * PL + p;
  int t0 = pr[0], t1 = pr[1], t2 = pr[2], t3 = pr[3];
  #pragma unroll
  for (int c = 0; c < 2; c++){
    int co = co2 * 2 + c;
    float a = b1[co] + sp[t0 * 161 + co] + sp[t1 * 161 + 40 + co]
            + sp[t2 * 161 + 80 + co] + sp[t3 * 161 + 120 + co];
    h1[(size_t)(b * NC1 + co) * L1P + p] = relu_(a);
  }
}

// ---- conv2: LDS whole-K tiled ----
#define C2XW 44
#define C2WP 324
__global__ __launch_bounds__(128) void k_c2(const float* __restrict__ h1,
                        const float* __restrict__ w, const float* __restrict__ bias,
                        float* __restrict__ h2){
  __shared__ float xs[NC1 * C2XW];
  __shared__ float wl[16 * C2WP];
  int blk = blockIdx.x;
  int pt = blk % 31; int t = blk / 31;
  int cog = t % 5; int b = t / 5;
  int co0 = cog * 16, pblk = pt * 32;
  int tid = threadIdx.x;
  const float* xb = h1 + (size_t)(b * NC1) * L1P + pblk;
  for (int i = tid; i < 440; i += 128){
    int r = i / 11, c = i % 11;
    *(float4*)(&xs[r * C2XW + c * 4]) = *(const float4*)(xb + (size_t)r * L1P + c * 4);
  }
  for (int i = tid; i < 1280; i += 128){
    int cc = i / 80, c = i % 80;
    *(float4*)(&wl[cc * C2WP + c * 4]) =
        *(const float4*)(w + (size_t)(co0 + cc) * 320 + c * 4);
  }
  __syncthreads();
  int co_l = tid >> 3, pg = tid & 7, p0 = pg * 4;
  float acc[4] = {0,0,0,0};
  const float* wc = &wl[co_l * C2WP];
  #pragma unroll 2
  for (int ci = 0; ci < NC1; ci++){
    const float* xrow = &xs[ci * C2XW + p0];
    float xv[12];
    *(float4*)(&xv[0]) = *(const float4*)(xrow);
    *(float4*)(&xv[4]) = *(const float4*)(xrow + 4);
    *(float4*)(&xv[8]) = *(const float4*)(xrow + 8);
    float wk[8];
    *(float4*)(&wk[0]) = *(const float4*)(wc + ci * 8);
    *(float4*)(&wk[4]) = *(const float4*)(wc + ci * 8 + 4);
    #pragma unroll
    for (int k = 0; k < 8; k++){
      #pragma unroll
      for (int pp = 0; pp < 4; pp++)
        acc[pp] = fmaf(xv[pp + k], wk[k], acc[pp]);
    }
  }
  int co = co0 + co_l;
  float bv = bias[co];
  int pbase = pblk + p0;
  float* yr = h2 + (size_t)(b * NC2 + co) * L2P + pbase;
  if (pbase + 3 < L2O){
    float4 o; o.x = relu_(acc[0] + bv); o.y = relu_(acc[1] + bv);
    o.z = relu_(acc[2] + bv); o.w = relu_(acc[3] + bv);
    *(float4*)yr = o;
  } else {
    #pragma unroll
    for (int pp = 0; pp < 4; pp++)
      if (pbase + pp < L2O) yr[pp] = relu_(acc[pp] + bv);
  }
}

// ---- transpose + bf16 cast: h2[b][ci][p] -> h2bT[b][p 992][ci 96] ----
__global__ __launch_bounds__(256) void k_t2(const float* __restrict__ h2,
                        unsigned short* __restrict__ h2bT){
  __shared__ float tile[32][33];
  int blk = blockIdx.x;
  int pt = blk % 31; int t = blk / 31;
  int cit = t % 3; int b = t / 3;
  int ci0 = cit * 32, p0 = pt * 32;
  int r = threadIdx.x >> 5, c = threadIdx.x & 31;
  #pragma unroll
  for (int rr = 0; rr < 4; rr++){
    int ci = ci0 + r * 4 + rr;
    float v = (ci < NC2) ? h2[(size_t)(b * NC2 + ci) * L2P + p0 + c] : 0.f;
    tile[r * 4 + rr][c] = v;
  }
  __syncthreads();
  #pragma unroll
  for (int rr = 0; rr < 4; rr++){
    int prow = p0 + r * 4 + rr;
    h2bT[((size_t)b * 992 + prow) * 96 + ci0 + c] = bf16_(tile[c][r * 4 + rr]);
  }
}

// ---- conv3 via MFMA bf16 ----
__global__ __launch_bounds__(256) void k_c3m(const unsigned short* __restrict__ h2bT,
                        const unsigned short* __restrict__ w3r,
                        const float* __restrict__ bias, float* __restrict__ pconv){
  int blk = blockIdx.x;
  int pt = blk % 16; int t = blk / 16;
  int cog = t % 10; int b = t / 10;
  int co0 = cog * 16;
  int wave = threadIdx.x >> 6, lane = threadIdx.x & 63;
  int col = lane & 15, g = lane >> 4;
  int p0 = pt * 64 + wave * 16;
  f32x4 acc = {0.f, 0.f, 0.f, 0.f};
  const unsigned short* wbase = w3r + (size_t)(co0 + col) * 96 + g * 8;
  const unsigned short* xbase = h2bT + (size_t)b * 992 * 96 + g * 8;
  int prow = p0 + col;
  for (int kk = 0; kk < 12; kk++){
    int rp = prow + kk; if (rp > 991) rp = 991;
    const unsigned short* xr = xbase + (size_t)rp * 96;
    const unsigned short* wr = wbase + (size_t)kk * (160 * 96);
    #pragma unroll
    for (int ks = 0; ks < 3; ks++){
      bf16x8 av = *(const bf16x8*)(wr + ks * 32);
      bf16x8 bv = *(const bf16x8*)(xr + ks * 32);
      acc = __builtin_amdgcn_mfma_f32_16x16x32_bf16(av, bv, acc, 0, 0, 0);
    }
  }
  if (p0 >= L3O) return;
  int p = p0 + col;
  if (p < L3O){
    #pragma unroll
    for (int r = 0; r < 4; r++){
      int co = co0 + g * 4 + r;
      pconv[(size_t)(b * NC3 + co) * L3P + p] = acc[r] + bias[co];
    }
  }
}

// ---- fused: blocks 0..159 drug-att (+enc init); blocks 160..799 protein-att ----
__global__ __launch_bounds__(128) void k_dpatt(const float* __restrict__ drug,
                        const int* __restrict__ natoms,
                        const float* __restrict__ Wd, const float* __restrict__ bd,
                        float* __restrict__ dattT, unsigned* __restrict__ enc,
                        const float* __restrict__ pconv,
                        const int* __restrict__ prot,
                        const float* __restrict__ Wp, const float* __restrict__ bp,
                        float* __restrict__ pattT){
  __shared__ float xs[160 * 68];
  __shared__ float wl[16 * 164];
  int blk = blockIdx.x;
  int tid = threadIdx.x;
  if (blk < 160){
    if (blk == 0){
      for (int k = tid; k < 2 * BB * NC3; k += 128) enc[k] = 0u;
    }
    int b = blk / 40, c0 = (blk % 40) * 4;
    for (int i = tid; i < DL; i += 128){
      const float4* xr = (const float4*)(drug + ((size_t)b * DL + i) * NC3);
      float4 a[4];
      #pragma unroll
      for (int cc = 0; cc < 4; cc++) a[cc] = make_float4(0.f, 0.f, 0.f, 0.f);
      for (int k4 = 0; k4 < 40; k4++){
        float4 xv = xr[k4];
        #pragma unroll
        for (int cc = 0; cc < 4; cc++){
          float4 wv = ((const float4*)(Wd + (size_t)(c0 + cc) * NC3))[k4];
          a[cc].x = fmaf(xv.x, wv.x, a[cc].x);
          a[cc].y = fmaf(xv.y, wv.y, a[cc].y);
          a[cc].z = fmaf(xv.z, wv.z, a[cc].z);
          a[cc].w = fmaf(xv.w, wv.w, a[cc].w);
        }
      }
      bool act = i < natoms[b];
      #pragma unroll
      for (int cc = 0; cc < 4; cc++){
        float r = act ? (a[cc].x + a[cc].y + a[cc].z + a[cc].w + bd[c0 + cc]) : 0.f;
        dattT[(size_t)(b * NC3 + c0 + cc) * DLP + i] = r;
      }
    }
    return;
  }
  int q = blk - 160;
  int jt = q & 15; int t = q >> 4;
  int cog = t % 10; int b = t / 10;
  int co0 = cog * 16, j0t = jt * 64;
  const float* xb = pconv + (size_t)(b * NC3) * L3P + j0t;
  for (int i = tid; i < 2720; i += 128){
    int r = i / 17, c = i % 17;
    float4 v = *(const float4*)(xb + (size_t)r * L3P + c * 4);
    *(float4*)(&xs[r * 68 + c * 4]) = relu4_(v);
  }
  for (int i = tid; i < 640; i += 128){
    int cc = i / 40, c = i % 40;
    *(float4*)(&wl[cc * 164 + c * 4]) =
        *(const float4*)(Wp + (size_t)(co0 + cc) * NC3 + c * 4);
  }
  __syncthreads();
  int cp = tid >> 4, jg = tid & 15;
  int j0 = jg * 4;
  float acc0[4] = {0,0,0,0}, acc1[4] = {0,0,0,0};
  const float* xcol = xs + j0;
  const float* w0r = wl + (cp * 2) * 164;
  const float* w1r = wl + (cp * 2 + 1) * 164;
  #pragma unroll 2
  for (int k4 = 0; k4 < 40; k4++){
    float4 wa = *(const float4*)(w0r + k4 * 4);
    float4 wb = *(const float4*)(w1r + k4 * 4);
    float4 x0 = *(const float4*)(xcol + (k4 * 4 + 0) * 68);
    float4 x1 = *(const float4*)(xcol + (k4 * 4 + 1) * 68);
    float4 x2 = *(const float4*)(xcol + (k4 * 4 + 2) * 68);
    float4 x3 = *(const float4*)(xcol + (k4 * 4 + 3) * 68);
    acc0[0] = fmaf(x0.x, wa.x, fmaf(x1.x, wa.y, fmaf(x2.x, wa.z, fmaf(x3.x, wa.w, acc0[0]))));
    acc0[1] = fmaf(x0.y, wa.x, fmaf(x1.y, wa.y, fmaf(x2.y, wa.z, fmaf(x3.y, wa.w, acc0[1]))));
    acc0[2] = fmaf(x0.z, wa.x, fmaf(x1.z, wa.y, fmaf(x2.z, wa.z, fmaf(x3.z, wa.w, acc0[2]))));
    acc0[3] = fmaf(x0.w, wa.x, fmaf(x1.w, wa.y, fmaf(x2.w, wa.z, fmaf(x3.w, wa.w, acc0[3]))));
    acc1[0] = fmaf(x0.x, wb.x, fmaf(x1.x, wb.y, fmaf(x2.x, wb.z, fmaf(x3.x, wb.w, acc1[0]))));
    acc1[1] = fmaf(x0.y, wb.x, fmaf(x1.y, wb.y, fmaf(x2.y, wb.z, fmaf(x3.y, wb.w, acc1[1]))));
    acc1[2] = fmaf(x0.z, wb.x, fmaf(x1.z, wb.y, fmaf(x2.z, wb.z, fmaf(x3.z, wb.w, acc1[2]))));
    acc1[3] = fmaf(x0.w, wb.x, fmaf(x1.w, wb.y, fmaf(x2.w, wb.z, fmaf(x3.w, wb.w, acc1[3]))));
  }
  int coA = co0 + cp * 2, coB = coA + 1;
  float bA = bp[coA], bB = bp[coB];
  int jb = j0t + j0;
  const int* pr = prot + b * PL;
  #pragma unroll
  for (int qq = 0; qq < 4; qq++){
    int j = jb + qq;
    if (j < L3O){
      bool act = pr[j] > 0;
      pattT[(size_t)(b * NC3 + coA) * PLP + j] = act ? (acc0[qq] + bA) : 0.f;
      pattT[(size_t)(b * NC3 + coB) * PLP + j] = act ? (acc1[qq] + bB) : 0.f;
    }
  }
}

// ---- means: balanced 600-task split + float4/4-acc ILP ----
__global__ __launch_bounds__(256) void k_means(const float* __restrict__ dattT,
                        const float* __restrict__ pattT,
                        float* __restrict__ cmeanT, float* __restrict__ pmeanT){
  __shared__ __align__(16) float sda[DLP];
  __shared__ __align__(16) float spa[PLP];
  __shared__ float scm[4][DLP];
  int b = blockIdx.x / NC3, c = blockIdx.x % NC3;
  int tid = threadIdx.x;
  const float4* dr = (const float4*)(dattT + (size_t)(b * NC3 + c) * DLP);
  const float4* pr = (const float4*)(pattT + (size_t)(b * NC3 + c) * PLP);
  if (tid < DLP / 4) *(float4*)(&sda[tid * 4]) = dr[tid];
  if (tid < PLP / 4) *(float4*)(&spa[tid * 4]) = pr[tid];
  __syncthreads();
  // cmean partials: 600 tasks = 150 i x 4 j-quarters (244,244,244,247); 16B-aligned
  for (int t = tid; t < 600; t += 256){
    int i = t >> 2, qq = t & 3;
    int js = qq * 244;
    int je = (qq == 3) ? L3O : js + 244;
    float v = sda[i];
    float s0 = 0.f, s1 = 0.f, s2 = 0.f, s3 = 0.f;
    const float4* p4 = (const float4*)(spa + js);
    int n4 = (je - js) >> 2;                 // 61
    for (int u = 0; u < n4; u++){
      float4 p = p4[u];
      s0 += relu_(v + p.x); s1 += relu_(v + p.y);
      s2 += relu_(v + p.z); s3 += relu_(v + p.w);
    }
    for (int j = js + n4 * 4; j < je; j++) s0 += relu_(v + spa[j]);
    scm[qq][i] = (s0 + s1) + (s2 + s3);
  }
  // pmean: thread j, float4 over i
  for (int j = tid; j < L3O; j += 256){
    float v = spa[j];
    float s0 = 0.f, s1 = 0.f, s2 = 0.f, s3 = 0.f;
    const float4* d4 = (const float4*)sda;
    #pragma unroll 4
    for (int u = 0; u < 37; u++){            // 148 elements
      float4 d = d4[u];
      s0 += relu_(v + d.x); s1 += relu_(v + d.y);
      s2 += relu_(v + d.z); s3 += relu_(v + d.w);
    }
    s0 += relu_(v + sda[148]); s1 += relu_(v + sda[149]);
    pmeanT[(size_t)(b * NC3 + c) * PLP + j] = ((s0 + s1) + (s2 + s3)) * (1.f / DL);
  }
  __syncthreads();
  if (tid < DL){
    float s = (scm[0][tid] + scm[1][tid]) + (scm[2][tid] + scm[3][tid]);
    cmeanT[(size_t)(b * NC3 + c) * DLP + tid] = s * (1.f / L3O);
  }
}

// ---- fused gates: blocks 0..159 compound; 160..799 protein ----
__global__ __launch_bounds__(128) void k_atte(const float* __restrict__ cmeanT,
                        const float* __restrict__ pmeanT,
                        const float* __restrict__ Watt, const float* __restrict__ batt,
                        const float* __restrict__ drug,
                        const float* __restrict__ pconv, unsigned* __restrict__ enc){
  __shared__ float xs[160 * 68];
  __shared__ float wl[16 * 164];
  int blk = blockIdx.x;
  int tid = threadIdx.x;
  if (blk < 160){
    __shared__ float sred[2][4];
    int b = blk / 40, c0 = (blk % 40) * 4;
    float m[4];
    #pragma unroll
    for (int cc = 0; cc < 4; cc++) m[cc] = NINF;
    for (int i = tid; i < DL; i += 128){
      float acc[4];
      #pragma unroll
      for (int cc = 0; cc < 4; cc++) acc[cc] = batt[c0 + cc];
      const float* xc = cmeanT + (size_t)b * NC3 * DLP + i;
      const float* wr = Watt + (size_t)c0 * NC3;
      for (int cb = 0; cb < NC3; cb += 32){
        float xv[32];
        #pragma unroll
        for (int u = 0; u < 32; u++) xv[u] = xc[(size_t)(cb + u) * DLP];
        #pragma unroll
        for (int u = 0; u < 32; u++){
          #pragma unroll
          for (int cc = 0; cc < 4; cc++)
            acc[cc] = fmaf(xv[u], wr[(size_t)cc * NC3 + cb + u], acc[cc]);
        }
      }
      const float* gr = drug + ((size_t)b * DL + i) * NC3 + c0;
      #pragma unroll
      for (int cc = 0; cc < 4; cc++){
        float atte = 1.f / (1.f + expf(-acc[cc]));
        m[cc] = fmaxf(m[cc], gr[cc] * (0.5f + atte));
      }
    }
    int wave = tid >> 6, lane = tid & 63;
    #pragma unroll
    for (int cc = 0; cc < 4; cc++){
      float v = m[cc];
      for (int off = 1; off < 64; off <<= 1) v = fmaxf(v, __shfl_xor(v, off, 64));
      if (lane == 0) sred[wave][cc] = v;
    }
    __syncthreads();
    if (tid < 4){
      float v = fmaxf(sred[0][tid], sred[1][tid]);
      atomicMax(&enc[b * NC3 + c0 + tid], fenc(v));
    }
    return;
  }
  int q = blk - 160;
  int jt = q & 15; int t = q >> 4;
  int cog = t % 10; int b = t / 10;
  int co0 = cog * 16, j0t = jt * 64;
  const float* xb = pmeanT + (size_t)(b * NC3) * PLP + j0t;
  for (int i = tid; i < 2720; i += 128){
    int r = i / 17, c = i % 17;
    *(float4*)(&xs[r * 68 + c * 4]) = *(const float4*)(xb + (size_t)r * PLP + c * 4);
  }
  for (int i = tid; i < 640; i += 128){
    int cc = i / 40, c = i % 40;
    *(float4*)(&wl[cc * 164 + c * 4]) =
        *(const float4*)(Watt + (size_t)(co0 + cc) * NC3 + c * 4);
  }
  __syncthreads();
  int cp = tid >> 4, jg = tid & 15;
  int j0 = jg * 4;
  float acc0[4] = {0,0,0,0}, acc1[4] = {0,0,0,0};
  const float* xcol = xs + j0;
  const float* w0r = wl + (cp * 2) * 164;
  const float* w1r = wl + (cp * 2 + 1) * 164;
  #pragma unroll 2
  for (int k4 = 0; k4 < 40; k4++){
    float4 wa = *(const float4*)(w0r + k4 * 4);
    float4 wb = *(const float4*)(w1r + k4 * 4);
    float4 x0 = *(const float4*)(xcol + (k4 * 4 + 0) * 68);
    float4 x1 = *(const float4*)(xcol + (k4 * 4 + 1) * 68);
    float4 x2 = *(const float4*)(xcol + (k4 * 4 + 2) * 68);
    float4 x3 = *(const float4*)(xcol + (k4 * 4 + 3) * 68);
    acc0[0] = fmaf(x0.x, wa.x, fmaf(x1.x, wa.y, fmaf(x2.x, wa.z, fmaf(x3.x, wa.w, acc0[0]))));
    acc0[1] = fmaf(x0.y, wa.x, fmaf(x1.y, wa.y, fmaf(x2.y, wa.z, fmaf(x3.y, wa.w, acc0[1]))));
    acc0[2] = fmaf(x0.z, wa.x, fmaf(x1.z, wa.y, fmaf(x2.z, wa.z, fmaf(x3.z, wa.w, acc0[2]))));
    acc0[3] = fmaf(x0.w, wa.x, fmaf(x1.w, wa.y, fmaf(x2.w, wa.z, fmaf(x3.w, wa.w, acc0[3]))));
    acc1[0] = fmaf(x0.x, wb.x, fmaf(x1.x, wb.y, fmaf(x2.x, wb.z, fmaf(x3.x, wb.w, acc1[0]))));
    acc1[1] = fmaf(x0.y, wb.x, fmaf(x1.y, wb.y, fmaf(x2.y, wb.z, fmaf(x3.y, wb.w, acc1[1]))));
    acc1[2] = fmaf(x0.z, wb.x, fmaf(x1.z, wb.y, fmaf(x2.z, wb.z, fmaf(x3.z, wb.w, acc1[2]))));
    acc1[3] = fmaf(x0.w, wb.x, fmaf(x1.w, wb.y, fmaf(x2.w, wb.z, fmaf(x3.w, wb.w, acc1[3]))));
  }
  int coA = co0 + cp * 2, coB = coA + 1;
  float bA = batt[coA], bB = batt[coB];
  int jb = j0t + j0;
  float mA = NINF, mB = NINF;
  if (jb < L3P){
    const float* rA = pconv + (size_t)(b * NC3 + coA) * L3P + jb;
    const float* rB = pconv + (size_t)(b * NC3 + coB) * L3P + jb;
    float4 a0 = *(const float4*)rA;
    float4 a1 = *(const float4*)rB;
    float pAr[4] = {a0.x, a0.y, a0.z, a0.w};
    float pBr[4] = {a1.x, a1.y, a1.z, a1.w};
    #pragma unroll
    for (int qq = 0; qq < 4; qq++){
      int j = jb + qq;
      if (j < L3O){
        float gA = 1.f / (1.f + expf(-(acc0[qq] + bA)));
        float gB = 1.f / (1.f + expf(-(acc1[qq] + bB)));
        mA = fmaxf(mA, relu_(pAr[qq]) * (0.5f + gA));
        mB = fmaxf(mB, relu_(pBr[qq]) * (0.5f + gB));
      }
    }
  }
  #pragma unroll
  for (int off = 1; off < 16; off <<= 1){
    mA = fmaxf(mA, __shfl_xor(mA, off, 64));
    mB = fmaxf(mB, __shfl_xor(mB, off, 64));
  }
  if (jg == 0){
    atomicMax(&enc[BB * NC3 + b * NC3 + coA], fenc(mA));
    atomicMax(&enc[BB * NC3 + b * NC3 + coB], fenc(mB));
  }
}

// ---- MLP 1: 320 -> 1024 ----
__global__ __launch_bounds__(256) void k_mlp1(const unsigned* __restrict__ enc,
                        const float* __restrict__ W1, const float* __restrict__ bf1,
                        float* __restrict__ f1){
  int b = blockIdx.x >> 6, og = blockIdx.x & 63;
  int o = og * 16 + (threadIdx.x >> 4);
  int q = threadIdx.x & 15;
  const float4* wr = (const float4*)(W1 + (size_t)o * 320);
  float4 a = make_float4(0.f, 0.f, 0.f, 0.f);
  #pragma unroll
  for (int mi = 0; mi < 5; mi++){
    int k4 = q + mi * 16;
    int k = k4 * 4;
    const unsigned* e = (k < 160) ? (enc + b * NC3 + k)
                                  : (enc + BB * NC3 + b * NC3 + (k - 160));
    float4 wv = wr[k4];
    a.x = fmaf(fdec(e[0]), wv.x, a.x);
    a.y = fmaf(fdec(e[1]), wv.y, a.y);
    a.z = fmaf(fdec(e[2]), wv.z, a.z);
    a.w = fmaf(fdec(e[3]), wv.w, a.w);
  }
  float r = a.x + a.y + a.z + a.w;
  r += __shfl_xor(r, 1, 64); r += __shfl_xor(r, 2, 64);
  r += __shfl_xor(r, 4, 64); r += __shfl_xor(r, 8, 64);
  if (q == 0) f1[b * 1024 + o] = lrelu_(r + bf1[o]);
}

// ---- MLP 2: 1024 -> 1024 ----
__global__ __launch_bounds__(256) void k_mlp2(const float* __restrict__ x,
                        const float* __restrict__ W, const float* __restrict__ bias,
                        float* __restrict__ y){
  int b = blockIdx.x >> 6, og = blockIdx.x & 63;
  int o = og * 16 + (threadIdx.x >> 4);
  int q = threadIdx.x & 15;
  const float4* wr = (const float4*)(W + (size_t)o * 1024);
  const float4* xr = (const float4*)(x + b * 1024);
  float4 a = make_float4(0.f, 0.f, 0.f, 0.f);
  #pragma unroll
  for (int mi = 0; mi < 16; mi++){
    int k4 = q + mi * 16;
    float4 wv = wr[k4], xv = xr[k4];
    a.x = fmaf(xv.x, wv.x, a.x);
    a.y = fmaf(xv.y, wv.y, a.y);
    a.z = fmaf(xv.z, wv.z, a.z);
    a.w = fmaf(xv.w, wv.w, a.w);
  }
  float r = a.x + a.y + a.z + a.w;
  r += __shfl_xor(r, 1, 64); r += __shfl_xor(r, 2, 64);
  r += __shfl_xor(r, 4, 64); r += __shfl_xor(r, 8, 64);
  if (q == 0) y[b * 1024 + o] = lrelu_(r + bias[o]);
}

// ---- MLP 3: 1024 -> 512 ----
__global__ __launch_bounds__(256) void k_mlp3(const float* __restrict__ x,
                        const float* __restrict__ W, const float* __restrict__ bias,
                        float* __restrict__ y){
  int b = blockIdx.x >> 5, og = blockIdx.x & 31;
  int o = og * 16 + (threadIdx.x >> 4);
  int q = threadIdx.x & 15;
  const float4* wr = (const float4*)(W + (size_t)o * 1024);
  const float4* xr = (const float4*)(x + b * 1024);
  float4 a = make_float4(0.f, 0.f, 0.f, 0.f);
  #pragma unroll
  for (int mi = 0; mi < 16; mi++){
    int k4 = q + mi * 16;
    float4 wv = wr[k4], xv = xr[k4];
    a.x = fmaf(xv.x, wv.x, a.x);
    a.y = fmaf(xv.y, wv.y, a.y);
    a.z = fmaf(xv.z, wv.z, a.z);
    a.w = fmaf(xv.w, wv.w, a.w);
  }
  float r = a.x + a.y + a.z + a.w;
  r += __shfl_xor(r, 1, 64); r += __shfl_xor(r, 2, 64);
  r += __shfl_xor(r, 4, 64); r += __shfl_xor(r, 8, 64);
  if (q == 0) y[b * 512 + o] = lrelu_(r + bias[o]);
}

// ---- MLP out: 512 -> 2 ----
__global__ void k_mlp4(const float* __restrict__ f3, const float* __restrict__ Wo,
                       const float* __restrict__ bo, float* __restrict__ out){
  int tid = threadIdx.x;
  int g = tid >> 5, lane = tid & 31;
  int b = g >> 1, o = g & 1;
  const float4* xr = (const float4*)(f3 + b * 512);
  const float4* wr = (const float4*)(Wo + o * 512);
  float4 a = make_float4(0.f, 0.f, 0.f, 0.f);
  #pragma unroll
  for (int mI = 0; mI < 4; mI++){
    int k4 = lane + mI * 32;
    float4 xv = xr[k4], wv = wr[k4];
    a.x = fmaf(xv.x, wv.x, a.x);
    a.y = fmaf(xv.y, wv.y, a.y);
    a.z = fmaf(xv.z, wv.z, a.z);
    a.w = fmaf(xv.w, wv.w, a.w);
  }
  float r = a.x + a.y + a.z + a.w;
  for (int off = 16; off; off >>= 1) r += __shfl_xor(r, off, 64);
  if (lane == 0) out[b * 2 + o] = r + bo[o];
}

extern "C" void kernel_launch(void* const* d_in, const int* in_sizes, int n_in,
                              void* d_out, int out_size, void* d_ws, size_t ws_size,
                              hipStream_t stream) {
  const float* drug  = (const float*)d_in[0];
  const int*   natoms= (const int*)d_in[1];
  const int*   prot  = (const int*)d_in[2];
  const float* emb   = (const float*)d_in[3];
  const float* w1    = (const float*)d_in[4];
  const float* b1    = (const float*)d_in[5];
  const float* w2    = (const float*)d_in[6];
  const float* b2    = (const float*)d_in[7];
  const float* w3    = (const float*)d_in[8];
  const float* b3    = (const float*)d_in[9];
  const float* Wd    = (const float*)d_in[10];
  const float* bd    = (const float*)d_in[11];
  const float* Wp    = (const float*)d_in[12];
  const float* bp    = (const float*)d_in[13];
  const float* Watt  = (const float*)d_in[14];
  const float* batt  = (const float*)d_in[15];
  const float* W1    = (const float*)d_in[16];
  const float* bf1   = (const float*)d_in[17];
  const float* W2    = (const float*)d_in[18];
  const float* bf2   = (const float*)d_in[19];
  const float* W3    = (const float*)d_in[20];
  const float* bf3   = (const float*)d_in[21];
  const float* Wo    = (const float*)d_in[22];
  const float* bo    = (const float*)d_in[23];
  float* out = (float*)d_out;

  float* ws = (float*)d_ws;
  float* h1     = ws;                       // 160000 (dead after k_c2)
  float* cmeanT = ws;                       // 97280 (reuse of h1 region)
  float* f1     = ws + 97280;               // 4096
  float* f2     = ws + 101376;              // 4096
  float* f3     = ws + 105472;              // 2048
  float* h2     = ws + 160000;              // 317440 (post-relu f32)
  float* pconv  = ws + 477440;              // 627200 (post-bias pre-relu f32)
  float* dattT  = ws + 1104640;             // 97280
  float* pattT  = ws + 1201920;             // 629760
  float* pmeanT = ws + 1831680;             // 629760
  unsigned* enc = (unsigned*)(ws + 2461440);// 1280 u32
  float* projG  = ws + 2461760;             // 4186
  unsigned short* h2bT = (unsigned short*)(ws + 2466048); // 380928 bf16
  unsigned short* w3r  = (unsigned short*)(ws + 2656512); // 184320 bf16

  k_prep  <<<737, 256, 0, stream>>>(emb, w1, projG, w3, w3r);
  k_conv1 <<<BB * 80, 256, 0, stream>>>(prot, projG, b1, h1);
  k_c2    <<<620, 128, 0, stream>>>(h1, w2, b2, h2);
  k_t2    <<<372, 256, 0, stream>>>(h2, h2bT);
  k_c3m   <<<640, 256, 0, stream>>>(h2bT, w3r, b3, pconv);
  k_dpatt <<<800, 128, 0, stream>>>(drug, natoms, Wd, bd, dattT, enc,
                                    pconv, prot, Wp, bp, pattT);
  k_means <<<BB * NC3, 256, 0, stream>>>(dattT, pattT, cmeanT, pmeanT);
  k_atte  <<<800, 128, 0, stream>>>(cmeanT, pmeanT, Watt, batt, drug,
                                    pconv, enc);
  k_mlp1  <<<256, 256, 0, stream>>>(enc, W1, bf1, f1);
  k_mlp2  <<<256, 256, 0, stream>>>(f1, W2, bf2, f2);
  k_mlp3  <<<128, 256, 0, stream>>>(f2, W3, bf3, f3);
  k_mlp4  <<<1, 256, 0, stream>>>(f3, Wo, bo, out);
}

// Round 11
// 106.154 us; speedup vs baseline: 1.7654x; 1.2351x over previous
//
#include <hip/hip_runtime.h>
#include <math.h>

#define BB 4
#define DL 150
#define PL 1000
#define CD 64
#define NC1 40
#define NC2 80
#define NC3 160
#define L1O 997
#define L2O 990
#define L3O 979
#define L1P 1000
#define L2P 992
#define L3P 980
#define DLP 152
#define PLP 984
#define JP 992
#define NINF (-1e30f)

typedef __attribute__((ext_vector_type(8))) short bf16x8;
typedef __attribute__((ext_vector_type(4))) float f32x4;

__device__ __forceinline__ float relu_(float x){ return fmaxf(x, 0.f); }
__device__ __forceinline__ float lrelu_(float x){ return x > 0.f ? x : 0.01f * x; }

__device__ __forceinline__ unsigned fenc(float x){
  unsigned u = __float_as_uint(x);
  return (u & 0x80000000u) ? ~u : (u | 0x80000000u);
}
__device__ __forceinline__ float fdec(unsigned u){
  return __uint_as_float((u & 0x80000000u) ? (u & 0x7fffffffu) : ~u);
}
__device__ __forceinline__ float4 relu4_(float4 v){
  v.x = fmaxf(v.x, 0.f); v.y = fmaxf(v.y, 0.f);
  v.z = fmaxf(v.z, 0.f); v.w = fmaxf(v.w, 0.f);
  return v;
}
__device__ __forceinline__ unsigned short bf16_(float x){
  unsigned u = __float_as_uint(x);
  unsigned r = (u + 0x7FFFu + ((u >> 16) & 1u)) >> 16;
  return (unsigned short)r;
}

// wave computes D[16co x 16j] = Wb[co][K=160] x Xb[j][K=160]^T (both bf16 row-major K-contig)
__device__ __forceinline__ f32x4 mfma_k160(const unsigned short* __restrict__ Wb,
                                           const unsigned short* __restrict__ Xb,
                                           int co0, int j0, int lane){
  int col = lane & 15, g = lane >> 4;
  f32x4 acc = {0.f, 0.f, 0.f, 0.f};
  const unsigned short* wr = Wb + (size_t)(co0 + col) * 160 + g * 8;
  const unsigned short* xr = Xb + (size_t)(j0 + col) * 160 + g * 8;
  #pragma unroll
  for (int k0 = 0; k0 < 5; k0++){
    bf16x8 av = *(const bf16x8*)(wr + k0 * 32);
    bf16x8 bv = *(const bf16x8*)(xr + k0 * 32);
    acc = __builtin_amdgcn_mfma_f32_16x16x32_bf16(av, bv, acc, 0, 0, 0);
  }
  return acc;
}

// ---- prep: 0..16 proj | 17..736 w3 reorder | 737..836 Wp cast | 837..936 Watt cast ----
__global__ __launch_bounds__(256) void k_prep(const float* __restrict__ emb,
                       const float* __restrict__ w1, float* __restrict__ projG,
                       const float* __restrict__ w3, unsigned short* __restrict__ w3r,
                       const float* __restrict__ Wp, unsigned short* __restrict__ Wpb,
                       const float* __restrict__ Watt, unsigned short* __restrict__ Wattb){
  int blk = blockIdx.x;
  if (blk < 17){
    int e = blk * 256 + threadIdx.x;
    if (e >= 26 * 160) return;
    int tok = e / 160, rem = e % 160, k = rem / 40, co = rem % 40;
    float a = 0.f;
    const float* er = emb + tok * CD;
    const float* wr = w1 + co * (CD * 4) + k;
    #pragma unroll 8
    for (int ci = 0; ci < CD; ci++) a = fmaf(er[ci], wr[ci * 4], a);
    projG[tok * 161 + k * 40 + co] = a;
    return;
  }
  if (blk < 737){
    int e = (blk - 17) * 256 + threadIdx.x;
    if (e >= 12 * 160 * 96) return;
    int kk = e / (160 * 96); int r = e % (160 * 96);
    int co = r / 96, ci = r % 96;
    float v = (ci < NC2) ? w3[(size_t)co * 960 + ci * 12 + kk] : 0.f;
    w3r[e] = bf16_(v);
    return;
  }
  if (blk < 837){
    int e = (blk - 737) * 256 + threadIdx.x;
    if (e < 160 * 160) Wpb[e] = bf16_(Wp[e]);
    return;
  }
  int e = (blk - 837) * 256 + threadIdx.x;
  if (e < 160 * 160) Wattb[e] = bf16_(Watt[e]);
}

// ---- conv1 apply (writes relu'd h1) ----
__global__ __launch_bounds__(256) void k_conv1(const int* __restrict__ prot,
                        const float* __restrict__ projG, const float* __restrict__ b1,
                        float* __restrict__ h1){
  __shared__ float sp[26 * 161];
  int b = blockIdx.x / 80;
  int t = (blockIdx.x % 80) * 256 + threadIdx.x;
  for (int k = threadIdx.x; k < 26 * 161; k += 256) sp[k] = projG[k];
  __syncthreads();
  int p = t & 1023, co2 = t >> 10;
  if (p >= L1O) return;
  const int* pr = prot + b * PL + p;
  int t0 = pr[0], t1 = pr[1], t2 = pr[2], t3 = pr[3];
  #pragma unroll
  for (int c = 0; c < 2; c++){
    int co = co2 * 2 + c;
    float a = b1[co] + sp[t0 * 161 + co] + sp[t1 * 161 + 40 + co]
            + sp[t2 * 161 + 80 + co] + sp[t3 * 161 + 120 + co];
    h1[(size_t)(b * NC1 + co) * L1P + p] = relu_(a);
  }
}

// ---- conv2: LDS whole-K tiled ----
#define C2XW 44
#define C2WP 324
__global__ __launch_bounds__(128) void k_c2(const float* __restrict__ h1,
                        const float* __restrict__ w, const float* __restrict__ bias,
                        float* __restrict__ h2){
  __shared__ float xs[NC1 * C2XW];
  __shared__ float wl[16 * C2WP];
  int blk = blockIdx.x;
  int pt = blk % 31; int t = blk / 31;
  int cog = t % 5; int b = t / 5;
  int co0 = cog * 16, pblk = pt * 32;
  int tid = threadIdx.x;
  const float* xb = h1 + (size_t)(b * NC1) * L1P + pblk;
  for (int i = tid; i < 440; i += 128){
    int r = i / 11, c = i % 11;
    *(float4*)(&xs[r * C2XW + c * 4]) = *(const float4*)(xb + (size_t)r * L1P + c * 4);
  }
  for (int i = tid; i < 1280; i += 128){
    int cc = i / 80, c = i % 80;
    *(float4*)(&wl[cc * C2WP + c * 4]) =
        *(const float4*)(w + (size_t)(co0 + cc) * 320 + c * 4);
  }
  __syncthreads();
  int co_l = tid >> 3, pg = tid & 7, p0 = pg * 4;
  float acc[4] = {0,0,0,0};
  const float* wc = &wl[co_l * C2WP];
  #pragma unroll 2
  for (int ci = 0; ci < NC1; ci++){
    const float* xrow = &xs[ci * C2XW + p0];
    float xv[12];
    *(float4*)(&xv[0]) = *(const float4*)(xrow);
    *(float4*)(&xv[4]) = *(const float4*)(xrow + 4);
    *(float4*)(&xv[8]) = *(const float4*)(xrow + 8);
    float wk[8];
    *(float4*)(&wk[0]) = *(const float4*)(wc + ci * 8);
    *(float4*)(&wk[4]) = *(const float4*)(wc + ci * 8 + 4);
    #pragma unroll
    for (int k = 0; k < 8; k++){
      #pragma unroll
      for (int pp = 0; pp < 4; pp++)
        acc[pp] = fmaf(xv[pp + k], wk[k], acc[pp]);
    }
  }
  int co = co0 + co_l;
  float bv = bias[co];
  int pbase = pblk + p0;
  float* yr = h2 + (size_t)(b * NC2 + co) * L2P + pbase;
  if (pbase + 3 < L2O){
    float4 o; o.x = relu_(acc[0] + bv); o.y = relu_(acc[1] + bv);
    o.z = relu_(acc[2] + bv); o.w = relu_(acc[3] + bv);
    *(float4*)yr = o;
  } else {
    #pragma unroll
    for (int pp = 0; pp < 4; pp++)
      if (pbase + pp < L2O) yr[pp] = relu_(acc[pp] + bv);
  }
}

// ---- transpose + bf16 cast: h2 -> h2bT[b][p 992][ci 96] ----
__global__ __launch_bounds__(256) void k_t2(const float* __restrict__ h2,
                        unsigned short* __restrict__ h2bT){
  __shared__ float tile[32][33];
  int blk = blockIdx.x;
  int pt = blk % 31; int t = blk / 31;
  int cit = t % 3; int b = t / 3;
  int ci0 = cit * 32, p0 = pt * 32;
  int r = threadIdx.x >> 5, c = threadIdx.x & 31;
  #pragma unroll
  for (int rr = 0; rr < 4; rr++){
    int ci = ci0 + r * 4 + rr;
    float v = (ci < NC2) ? h2[(size_t)(b * NC2 + ci) * L2P + p0 + c] : 0.f;
    tile[r * 4 + rr][c] = v;
  }
  __syncthreads();
  #pragma unroll
  for (int rr = 0; rr < 4; rr++){
    int prow = p0 + r * 4 + rr;
    h2bT[((size_t)b * 992 + prow) * 96 + ci0 + c] = bf16_(tile[c][r * 4 + rr]);
  }
}

// ---- conv3 via MFMA bf16; also emits pconvTb = relu'd bf16 [b][p][co] ----
__global__ __launch_bounds__(256) void k_c3m(const unsigned short* __restrict__ h2bT,
                        const unsigned short* __restrict__ w3r,
                        const float* __restrict__ bias, float* __restrict__ pconv,
                        unsigned short* __restrict__ pconvTb){
  int blk = blockIdx.x;
  int pt = blk % 16; int t = blk / 16;
  int cog = t % 10; int b = t / 10;
  int co0 = cog * 16;
  int wave = threadIdx.x >> 6, lane = threadIdx.x & 63;
  int col = lane & 15, g = lane >> 4;
  int p0 = pt * 64 + wave * 16;
  f32x4 acc = {0.f, 0.f, 0.f, 0.f};
  const unsigned short* wbase = w3r + (size_t)(co0 + col) * 96 + g * 8;
  const unsigned short* xbase = h2bT + (size_t)b * 992 * 96 + g * 8;
  int prow = p0 + col;
  for (int kk = 0; kk < 12; kk++){
    int rp = prow + kk; if (rp > 991) rp = 991;
    const unsigned short* xr = xbase + (size_t)rp * 96;
    const unsigned short* wr = wbase + (size_t)kk * (160 * 96);
    #pragma unroll
    for (int ks = 0; ks < 3; ks++){
      bf16x8 av = *(const bf16x8*)(wr + ks * 32);
      bf16x8 bv = *(const bf16x8*)(xr + ks * 32);
      acc = __builtin_amdgcn_mfma_f32_16x16x32_bf16(av, bv, acc, 0, 0, 0);
    }
  }
  if (p0 >= L3O) return;
  int p = p0 + col;
  if (p < L3O){
    unsigned short tb[4];
    #pragma unroll
    for (int r = 0; r < 4; r++){
      int co = co0 + g * 4 + r;
      float v = acc[r] + bias[co];
      pconv[(size_t)(b * NC3 + co) * L3P + p] = v;
      tb[r] = bf16_(relu_(v));
    }
    *(uint2*)(&pconvTb[((size_t)b * JP + p) * 160 + co0 + g * 4]) = *(uint2*)tb;
  }
}

// ---- patt: blocks 0..159 drug-att f32 (+enc init); blocks 160..407 protein-att MFMA ----
__global__ __launch_bounds__(256) void k_patt(const float* __restrict__ drug,
                        const int* __restrict__ natoms,
                        const float* __restrict__ Wd, const float* __restrict__ bd,
                        float* __restrict__ dattT, unsigned* __restrict__ enc,
                        const unsigned short* __restrict__ pconvTb,
                        const int* __restrict__ prot,
                        const unsigned short* __restrict__ Wpb,
                        const float* __restrict__ bp, float* __restrict__ pattT){
  int blk = blockIdx.x;
  int tid = threadIdx.x;
  if (blk < 160){
    if (blk == 0){
      for (int k = tid; k < 2 * BB * NC3; k += 256) enc[k] = 0u;
    }
    int b = blk / 40, c0 = (blk % 40) * 4;
    int i = tid;
    if (i >= DL) return;
    const float4* xr = (const float4*)(drug + ((size_t)b * DL + i) * NC3);
    float4 a[4];
    #pragma unroll
    for (int cc = 0; cc < 4; cc++) a[cc] = make_float4(0.f, 0.f, 0.f, 0.f);
    for (int k4 = 0; k4 < 40; k4++){
      float4 xv = xr[k4];
      #pragma unroll
      for (int cc = 0; cc < 4; cc++){
        float4 wv = ((const float4*)(Wd + (size_t)(c0 + cc) * NC3))[k4];
        a[cc].x = fmaf(xv.x, wv.x, a[cc].x);
        a[cc].y = fmaf(xv.y, wv.y, a[cc].y);
        a[cc].z = fmaf(xv.z, wv.z, a[cc].z);
        a[cc].w = fmaf(xv.w, wv.w, a[cc].w);
      }
    }
    bool act = i < natoms[b];
    #pragma unroll
    for (int cc = 0; cc < 4; cc++){
      float r = act ? (a[cc].x + a[cc].y + a[cc].z + a[cc].w + bd[c0 + cc]) : 0.f;
      dattT[(size_t)(b * NC3 + c0 + cc) * DLP + i] = r;
    }
    return;
  }
  int q = blk - 160;                 // 0..247
  int jt = q % 62, b = q / 62;
  int j0 = jt * 16;
  int wave = tid >> 6, lane = tid & 63;
  int col = lane & 15, g = lane >> 4;
  const unsigned short* Xb = pconvTb + (size_t)b * JP * 160;
  for (int ct = wave; ct < 10; ct += 4){
    int co0 = ct * 16;
    f32x4 acc = mfma_k160(Wpb, Xb, co0, j0, lane);
    int j = j0 + col;
    if (j < L3O){
      bool act = prot[b * PL + j] > 0;
      #pragma unroll
      for (int r = 0; r < 4; r++){
        int co = co0 + g * 4 + r;
        pattT[(size_t)(b * NC3 + co) * PLP + j] = act ? (acc[r] + bp[co]) : 0.f;
      }
    }
  }
}

// ---- means: balanced 600-task split + float4/4-acc; also emits pmeanTb bf16 [b][j][c] ----
__global__ __launch_bounds__(256) void k_means(const float* __restrict__ dattT,
                        const float* __restrict__ pattT,
                        float* __restrict__ cmeanT, float* __restrict__ pmeanT,
                        unsigned short* __restrict__ pmeanTb){
  __shared__ __align__(16) float sda[DLP];
  __shared__ __align__(16) float spa[PLP];
  __shared__ float scm[4][DLP];
  int b = blockIdx.x / NC3, c = blockIdx.x % NC3;
  int tid = threadIdx.x;
  const float4* dr = (const float4*)(dattT + (size_t)(b * NC3 + c) * DLP);
  const float4* pr = (const float4*)(pattT + (size_t)(b * NC3 + c) * PLP);
  if (tid < DLP / 4) *(float4*)(&sda[tid * 4]) = dr[tid];
  if (tid < PLP / 4) *(float4*)(&spa[tid * 4]) = pr[tid];
  __syncthreads();
  for (int t = tid; t < 600; t += 256){
    int i = t >> 2, qq = t & 3;
    int js = qq * 244;
    int je = (qq == 3) ? L3O : js + 244;
    float v = sda[i];
    float s0 = 0.f, s1 = 0.f, s2 = 0.f, s3 = 0.f;
    const float4* p4 = (const float4*)(spa + js);
    int n4 = (je - js) >> 2;
    for (int u = 0; u < n4; u++){
      float4 p = p4[u];
      s0 += relu_(v + p.x); s1 += relu_(v + p.y);
      s2 += relu_(v + p.z); s3 += relu_(v + p.w);
    }
    for (int j = js + n4 * 4; j < je; j++) s0 += relu_(v + spa[j]);
    scm[qq][i] = (s0 + s1) + (s2 + s3);
  }
  for (int j = tid; j < L3O; j += 256){
    float v = spa[j];
    float s0 = 0.f, s1 = 0.f, s2 = 0.f, s3 = 0.f;
    const float4* d4 = (const float4*)sda;
    #pragma unroll 4
    for (int u = 0; u < 37; u++){
      float4 d = d4[u];
      s0 += relu_(v + d.x); s1 += relu_(v + d.y);
      s2 += relu_(v + d.z); s3 += relu_(v + d.w);
    }
    s0 += relu_(v + sda[148]); s1 += relu_(v + sda[149]);
    float pm = ((s0 + s1) + (s2 + s3)) * (1.f / DL);
    pmeanT[(size_t)(b * NC3 + c) * PLP + j] = pm;
    pmeanTb[((size_t)b * JP + j) * 160 + c] = bf16_(pm);
  }
  __syncthreads();
  if (tid < DL){
    float s = (scm[0][tid] + scm[1][tid]) + (scm[2][tid] + scm[3][tid]);
    cmeanT[(size_t)(b * NC3 + c) * DLP + tid] = s * (1.f / L3O);
  }
}

// ---- atte: blocks 0..159 compound f32; blocks 160..407 protein gate MFMA ----
__global__ __launch_bounds__(256) void k_atte(const float* __restrict__ cmeanT,
                        const unsigned short* __restrict__ pmeanTb,
                        const float* __restrict__ Watt,
                        const unsigned short* __restrict__ Wattb,
                        const float* __restrict__ batt,
                        const float* __restrict__ drug,
                        const float* __restrict__ pconv, unsigned* __restrict__ enc){
  int blk = blockIdx.x;
  int tid = threadIdx.x;
  if (blk < 160){
    __shared__ float sred[4][4];
    int b = blk / 40, c0 = (blk % 40) * 4;
    float m[4];
    #pragma unroll
    for (int cc = 0; cc < 4; cc++) m[cc] = NINF;
    int i = tid;
    if (i < DL){
      float acc[4];
      #pragma unroll
      for (int cc = 0; cc < 4; cc++) acc[cc] = batt[c0 + cc];
      const float* xc = cmeanT + (size_t)b * NC3 * DLP + i;
      const float* wr = Watt + (size_t)c0 * NC3;
      for (int cb = 0; cb < NC3; cb += 32){
        float xv[32];
        #pragma unroll
        for (int u = 0; u < 32; u++) xv[u] = xc[(size_t)(cb + u) * DLP];
        #pragma unroll
        for (int u = 0; u < 32; u++){
          #pragma unroll
          for (int cc = 0; cc < 4; cc++)
            acc[cc] = fmaf(xv[u], wr[(size_t)cc * NC3 + cb + u], acc[cc]);
        }
      }
      const float* gr = drug + ((size_t)b * DL + i) * NC3 + c0;
      #pragma unroll
      for (int cc = 0; cc < 4; cc++){
        float atte = 1.f / (1.f + expf(-acc[cc]));
        m[cc] = gr[cc] * (0.5f + atte);
      }
    }
    int wave = tid >> 6, lane = tid & 63;
    #pragma unroll
    for (int cc = 0; cc < 4; cc++){
      float v = m[cc];
      for (int off = 1; off < 64; off <<= 1) v = fmaxf(v, __shfl_xor(v, off, 64));
      if (lane == 0) sred[wave][cc] = v;
    }
    __syncthreads();
    if (tid < 4){
      float v = fmaxf(fmaxf(sred[0][tid], sred[1][tid]),
                      fmaxf(sred[2][tid], sred[3][tid]));
      atomicMax(&enc[b * NC3 + c0 + tid], fenc(v));
    }
    return;
  }
  int q = blk - 160;
  int jt = q % 62, b = q / 62;
  int j0 = jt * 16;
  int wave = tid >> 6, lane = tid & 63;
  int col = lane & 15, g = lane >> 4;
  const unsigned short* Xb = pmeanTb + (size_t)b * JP * 160;
  for (int ct = wave; ct < 10; ct += 4){
    int co0 = ct * 16;
    f32x4 acc = mfma_k160(Wattb, Xb, co0, j0, lane);
    int j = j0 + col;
    float m[4];
    #pragma unroll
    for (int r = 0; r < 4; r++){
      int co = co0 + g * 4 + r;
      if (j < L3O){
        float gate = 1.f / (1.f + expf(-(acc[r] + batt[co])));
        float pv = relu_(pconv[(size_t)(b * NC3 + co) * L3P + j]);
        m[r] = pv * (0.5f + gate);
      } else m[r] = NINF;
    }
    #pragma unroll
    for (int r = 0; r < 4; r++){
      #pragma unroll
      for (int off = 1; off < 16; off <<= 1)
        m[r] = fmaxf(m[r], __shfl_xor(m[r], off, 64));
    }
    if (col == 0){
      #pragma unroll
      for (int r = 0; r < 4; r++)
        atomicMax(&enc[BB * NC3 + b * NC3 + co0 + g * 4 + r], fenc(m[r]));
    }
  }
}

// ---- MLP 1: 320 -> 1024 ----
__global__ __launch_bounds__(256) void k_mlp1(const unsigned* __restrict__ enc,
                        const float* __restrict__ W1, const float* __restrict__ bf1,
                        float* __restrict__ f1){
  int b = blockIdx.x >> 6, og = blockIdx.x & 63;
  int o = og * 16 + (threadIdx.x >> 4);
  int q = threadIdx.x & 15;
  const float4* wr = (const float4*)(W1 + (size_t)o * 320);
  float4 a = make_float4(0.f, 0.f, 0.f, 0.f);
  #pragma unroll
  for (int mi = 0; mi < 5; mi++){
    int k4 = q + mi * 16;
    int k = k4 * 4;
    const unsigned* e = (k < 160) ? (enc + b * NC3 + k)
                                  : (enc + BB * NC3 + b * NC3 + (k - 160));
    float4 wv = wr[k4];
    a.x = fmaf(fdec(e[0]), wv.x, a.x);
    a.y = fmaf(fdec(e[1]), wv.y, a.y);
    a.z = fmaf(fdec(e[2]), wv.z, a.z);
    a.w = fmaf(fdec(e[3]), wv.w, a.w);
  }
  float r = a.x + a.y + a.z + a.w;
  r += __shfl_xor(r, 1, 64); r += __shfl_xor(r, 2, 64);
  r += __shfl_xor(r, 4, 64); r += __shfl_xor(r, 8, 64);
  if (q == 0) f1[b * 1024 + o] = lrelu_(r + bf1[o]);
}

// ---- MLP 2: 1024 -> 1024 ----
__global__ __launch_bounds__(256) void k_mlp2(const float* __restrict__ x,
                        const float* __restrict__ W, const float* __restrict__ bias,
                        float* __restrict__ y){
  int b = blockIdx.x >> 6, og = blockIdx.x & 63;
  int o = og * 16 + (threadIdx.x >> 4);
  int q = threadIdx.x & 15;
  const float4* wr = (const float4*)(W + (size_t)o * 1024);
  const float4* xr = (const float4*)(x + b * 1024);
  float4 a = make_float4(0.f, 0.f, 0.f, 0.f);
  #pragma unroll
  for (int mi = 0; mi < 16; mi++){
    int k4 = q + mi * 16;
    float4 wv = wr[k4], xv = xr[k4];
    a.x = fmaf(xv.x, wv.x, a.x);
    a.y = fmaf(xv.y, wv.y, a.y);
    a.z = fmaf(xv.z, wv.z, a.z);
    a.w = fmaf(xv.w, wv.w, a.w);
  }
  float r = a.x + a.y + a.z + a.w;
  r += __shfl_xor(r, 1, 64); r += __shfl_xor(r, 2, 64);
  r += __shfl_xor(r, 4, 64); r += __shfl_xor(r, 8, 64);
  if (q == 0) y[b * 1024 + o] = lrelu_(r + bias[o]);
}

// ---- MLP 3: 1024 -> 512 ----
__global__ __launch_bounds__(256) void k_mlp3(const float* __restrict__ x,
                        const float* __restrict__ W, const float* __restrict__ bias,
                        float* __restrict__ y){
  int b = blockIdx.x >> 5, og = blockIdx.x & 31;
  int o = og * 16 + (threadIdx.x >> 4);
  int q = threadIdx.x & 15;
  const float4* wr = (const float4*)(W + (size_t)o * 1024);
  const float4* xr = (const float4*)(x + b * 1024);
  float4 a = make_float4(0.f, 0.f, 0.f, 0.f);
  #pragma unroll
  for (int mi = 0; mi < 16; mi++){
    int k4 = q + mi * 16;
    float4 wv = wr[k4], xv = xr[k4];
    a.x = fmaf(xv.x, wv.x, a.x);
    a.y = fmaf(xv.y, wv.y, a.y);
    a.z = fmaf(xv.z, wv.z, a.z);
    a.w = fmaf(xv.w, wv.w, a.w);
  }
  float r = a.x + a.y + a.z + a.w;
  r += __shfl_xor(r, 1, 64); r += __shfl_xor(r, 2, 64);
  r += __shfl_xor(r, 4, 64); r += __shfl_xor(r, 8, 64);
  if (q == 0) y[b * 512 + o] = lrelu_(r + bias[o]);
}

// ---- MLP out: 512 -> 2 ----
__global__ void k_mlp4(const float* __restrict__ f3, const float* __restrict__ Wo,
                       const float* __restrict__ bo, float* __restrict__ out){
  int tid = threadIdx.x;
  int g = tid >> 5, lane = tid & 31;
  int b = g >> 1, o = g & 1;
  const float4* xr = (const float4*)(f3 + b * 512);
  const float4* wr = (const float4*)(Wo + o * 512);
  float4 a = make_float4(0.f, 0.f, 0.f, 0.f);
  #pragma unroll
  for (int mI = 0; mI < 4; mI++){
    int k4 = lane + mI * 32;
    float4 xv = xr[k4], wv = wr[k4];
    a.x = fmaf(xv.x, wv.x, a.x);
    a.y = fmaf(xv.y, wv.y, a.y);
    a.z = fmaf(xv.z, wv.z, a.z);
    a.w = fmaf(xv.w, wv.w, a.w);
  }
  float r = a.x + a.y + a.z + a.w;
  for (int off = 16; off; off >>= 1) r += __shfl_xor(r, off, 64);
  if (lane == 0) out[b * 2 + o] = r + bo[o];
}

extern "C" void kernel_launch(void* const* d_in, const int* in_sizes, int n_in,
                              void* d_out, int out_size, void* d_ws, size_t ws_size,
                              hipStream_t stream) {
  const float* drug  = (const float*)d_in[0];
  const int*   natoms= (const int*)d_in[1];
  const int*   prot  = (const int*)d_in[2];
  const float* emb   = (const float*)d_in[3];
  const float* w1    = (const float*)d_in[4];
  const float* b1    = (const float*)d_in[5];
  const float* w2    = (const float*)d_in[6];
  const float* b2    = (const float*)d_in[7];
  const float* w3    = (const float*)d_in[8];
  const float* b3    = (const float*)d_in[9];
  const float* Wd    = (const float*)d_in[10];
  const float* bd    = (const float*)d_in[11];
  const float* Wp    = (const float*)d_in[12];
  const float* bp    = (const float*)d_in[13];
  const float* Watt  = (const float*)d_in[14];
  const float* batt  = (const float*)d_in[15];
  const float* W1    = (const float*)d_in[16];
  const float* bf1   = (const float*)d_in[17];
  const float* W2    = (const float*)d_in[18];
  const float* bf2   = (const float*)d_in[19];
  const float* W3    = (const float*)d_in[20];
  const float* bf3   = (const float*)d_in[21];
  const float* Wo    = (const float*)d_in[22];
  const float* bo    = (const float*)d_in[23];
  float* out = (float*)d_out;

  float* ws = (float*)d_ws;
  float* h1     = ws;                       // 160000 (dead after k_c2)
  float* cmeanT = ws;                       // 97280 (reuse of h1 region)
  float* f1     = ws + 97280;               // 4096
  float* f2     = ws + 101376;              // 4096
  float* f3     = ws + 105472;              // 2048
  float* h2     = ws + 160000;              // 317440 (post-relu f32)
  float* pconv  = ws + 477440;              // 627200 (post-bias pre-relu f32)
  float* dattT  = ws + 1104640;             // 97280
  float* pattT  = ws + 1201920;             // 629760
  float* pmeanT = ws + 1831680;             // 629760
  unsigned* enc = (unsigned*)(ws + 2461440);// 1280 u32
  float* projG  = ws + 2461760;             // 4186
  unsigned short* h2bT = (unsigned short*)(ws + 2466048);    // 380928 bf16
  unsigned short* w3r  = (unsigned short*)(ws + 2656512);    // 184320 bf16
  unsigned short* pconvTb = (unsigned short*)(ws + 2748672); // 4*992*160 bf16
  unsigned short* pmeanTb = (unsigned short*)(ws + 3066112); // 4*992*160 bf16
  unsigned short* Wpb   = (unsigned short*)(ws + 3383552);   // 25600 bf16
  unsigned short* Wattb = (unsigned short*)(ws + 3396352);   // 25600 bf16

  k_prep  <<<937, 256, 0, stream>>>(emb, w1, projG, w3, w3r, Wp, Wpb, Watt, Wattb);
  k_conv1 <<<BB * 80, 256, 0, stream>>>(prot, projG, b1, h1);
  k_c2    <<<620, 128, 0, stream>>>(h1, w2, b2, h2);
  k_t2    <<<372, 256, 0, stream>>>(h2, h2bT);
  k_c3m   <<<640, 256, 0, stream>>>(h2bT, w3r, b3, pconv, pconvTb);
  k_patt  <<<408, 256, 0, stream>>>(drug, natoms, Wd, bd, dattT, enc,
                                    pconvTb, prot, Wpb, bp, pattT);
  k_means <<<BB * NC3, 256, 0, stream>>>(dattT, pattT, cmeanT, pmeanT, pmeanTb);
  k_atte  <<<408, 256, 0, stream>>>(cmeanT, pmeanTb, Watt, Wattb, batt, drug,
                                    pconv, enc);
  k_mlp1  <<<256, 256, 0, stream>>>(enc, W1, bf1, f1);
  k_mlp2  <<<256, 256, 0, stream>>>(f1, W2, bf2, f2);
  k_mlp3  <<<128, 256, 0, stream>>>(f2, W3, bf3, f3);
  k_mlp4  <<<1, 256, 0, stream>>>(f3, Wo, bo, out);
}

// Round 12
// 98.468 us; speedup vs baseline: 1.9032x; 1.0781x over previous
//
#include <hip/hip_runtime.h>
#include <math.h>

#define BB 4
#define DL 150
#define PL 1000
#define CD 64
#define NC1 40
#define NC2 80
#define NC3 160
#define L1O 997
#define L2O 990
#define L3O 979
#define L3P 980
#define DLP 152
#define PLP 984
#define JP 992
#define NINF (-1e30f)

typedef __attribute__((ext_vector_type(8))) short bf16x8;
typedef __attribute__((ext_vector_type(4))) float f32x4;

__device__ __forceinline__ float relu_(float x){ return fmaxf(x, 0.f); }
__device__ __forceinline__ float lrelu_(float x){ return x > 0.f ? x : 0.01f * x; }

__device__ __forceinline__ unsigned fenc(float x){
  unsigned u = __float_as_uint(x);
  return (u & 0x80000000u) ? ~u : (u | 0x80000000u);
}
__device__ __forceinline__ float fdec(unsigned u){
  return __uint_as_float((u & 0x80000000u) ? (u & 0x7fffffffu) : ~u);
}
__device__ __forceinline__ unsigned short bf16_(float x){
  unsigned u = __float_as_uint(x);
  unsigned r = (u + 0x7FFFu + ((u >> 16) & 1u)) >> 16;
  return (unsigned short)r;
}

// wave computes D[16co x 16j] = Wb[co][K=160] x Xb[j][K=160]^T (bf16, K-contig rows)
__device__ __forceinline__ f32x4 mfma_k160(const unsigned short* __restrict__ Wb,
                                           const unsigned short* __restrict__ Xb,
                                           int co0, int j0, int lane){
  int col = lane & 15, g = lane >> 4;
  f32x4 acc = {0.f, 0.f, 0.f, 0.f};
  const unsigned short* wr = Wb + (size_t)(co0 + col) * 160 + g * 8;
  const unsigned short* xr = Xb + (size_t)(j0 + col) * 160 + g * 8;
  #pragma unroll
  for (int k0 = 0; k0 < 5; k0++){
    bf16x8 av = *(const bf16x8*)(wr + k0 * 32);
    bf16x8 bv = *(const bf16x8*)(xr + k0 * 32);
    acc = __builtin_amdgcn_mfma_f32_16x16x32_bf16(av, bv, acc, 0, 0, 0);
  }
  return acc;
}

// ---- prep: proj | w3r | Wpb | Wattb | Wdb | w2r | drugb ----
__global__ __launch_bounds__(256) void k_prep(const float* __restrict__ emb,
                       const float* __restrict__ w1, float* __restrict__ projG,
                       const float* __restrict__ w3, unsigned short* __restrict__ w3r,
                       const float* __restrict__ Wp, unsigned short* __restrict__ Wpb,
                       const float* __restrict__ Watt, unsigned short* __restrict__ Wattb,
                       const float* __restrict__ Wd, unsigned short* __restrict__ Wdb,
                       const float* __restrict__ w2, unsigned short* __restrict__ w2r,
                       const float* __restrict__ drug, unsigned short* __restrict__ drugb){
  int blk = blockIdx.x;
  if (blk < 17){
    int e = blk * 256 + threadIdx.x;
    if (e >= 26 * 160) return;
    int tok = e / 160, rem = e % 160, k = rem / 40, co = rem % 40;
    float a = 0.f;
    const float* er = emb + tok * CD;
    const float* wr = w1 + co * (CD * 4) + k;
    #pragma unroll 8
    for (int ci = 0; ci < CD; ci++) a = fmaf(er[ci], wr[ci * 4], a);
    projG[tok * 161 + k * 40 + co] = a;
    return;
  }
  if (blk < 737){
    int e = (blk - 17) * 256 + threadIdx.x;
    int kk = e / (160 * 96); int r = e % (160 * 96);
    int co = r / 96, ci = r % 96;
    float v = (ci < NC2) ? w3[(size_t)co * 960 + ci * 12 + kk] : 0.f;
    w3r[e] = bf16_(v);
    return;
  }
  if (blk < 837){
    int e = (blk - 737) * 256 + threadIdx.x;
    Wpb[e] = bf16_(Wp[e]);
    return;
  }
  if (blk < 937){
    int e = (blk - 837) * 256 + threadIdx.x;
    Wattb[e] = bf16_(Watt[e]);
    return;
  }
  if (blk < 1037){
    int e = (blk - 937) * 256 + threadIdx.x;
    Wdb[e] = bf16_(Wd[e]);
    return;
  }
  if (blk < 1197){
    int e = (blk - 1037) * 256 + threadIdx.x;   // [kk8][co80][ci64]
    int kk = e / (80 * 64); int r = e % (80 * 64);
    int co = r / 64, ci = r % 64;
    float v = (ci < NC1) ? w2[(size_t)(co * NC1 + ci) * 8 + kk] : 0.f;
    w2r[e] = bf16_(v);
    return;
  }
  {
    int e = (blk - 1197) * 256 + threadIdx.x;   // [b][i160][c160]
    int b = e / 25600; int r = e % 25600;
    int i = r / 160, c = r % 160;
    float v = (i < DL) ? drug[((size_t)b * DL + i) * 160 + c] : 0.f;
    drugb[e] = bf16_(v);
  }
}

// ---- conv1: embed+K4 conv, writes relu'd bf16 h1bT[b][1000][64] (ci/p padded) ----
__global__ __launch_bounds__(256) void k_conv1(const int* __restrict__ prot,
                        const float* __restrict__ projG, const float* __restrict__ b1,
                        unsigned short* __restrict__ h1bT){
  __shared__ float sp[26 * 161];
  int b = blockIdx.x / 125;
  int t = (blockIdx.x % 125) * 256 + threadIdx.x;   // 0..31999
  for (int k = threadIdx.x; k < 26 * 161; k += 256) sp[k] = projG[k];
  __syncthreads();
  int ci = (t & 31) * 2, p = t >> 5;                // p 0..999
  float v0 = 0.f, v1 = 0.f;
  if (p < L1O && ci < NC1){
    const int* pr = prot + b * PL + p;
    int t0 = pr[0], t1 = pr[1], t2 = pr[2], t3 = pr[3];
    v0 = relu_(b1[ci] + sp[t0 * 161 + ci] + sp[t1 * 161 + 40 + ci]
             + sp[t2 * 161 + 80 + ci] + sp[t3 * 161 + 120 + ci]);
    int c1 = ci + 1;
    v1 = relu_(b1[c1] + sp[t0 * 161 + c1] + sp[t1 * 161 + 40 + c1]
             + sp[t2 * 161 + 80 + c1] + sp[t3 * 161 + 120 + c1]);
  }
  ushort2 o; o.x = bf16_(v0); o.y = bf16_(v1);
  *(ushort2*)(&h1bT[((size_t)b * 1000 + p) * 64 + ci]) = o;
}

// ---- conv2 via MFMA: grid 320 = b4 x cog5 x pt16(64p); writes relu'd bf16 h2bT ----
__global__ __launch_bounds__(256) void k_c2m(const unsigned short* __restrict__ h1bT,
                        const unsigned short* __restrict__ w2r,
                        const float* __restrict__ bias,
                        unsigned short* __restrict__ h2bT){
  int blk = blockIdx.x;
  int pt = blk % 16; int t = blk / 16;
  int cog = t % 5; int b = t / 5;
  int co0 = cog * 16;
  int wave = threadIdx.x >> 6, lane = threadIdx.x & 63;
  int col = lane & 15, g = lane >> 4;
  int p0 = pt * 64 + wave * 16;
  if (p0 >= JP) return;
  f32x4 acc = {0.f, 0.f, 0.f, 0.f};
  const unsigned short* wbase = w2r + (size_t)(co0 + col) * 64 + g * 8;
  const unsigned short* xbase = h1bT + (size_t)b * 1000 * 64 + g * 8;
  int prow = p0 + col;
  #pragma unroll 2
  for (int kk = 0; kk < 8; kk++){
    int rp = prow + kk; if (rp > 999) rp = 999;
    const unsigned short* xr = xbase + (size_t)rp * 64;
    const unsigned short* wr = wbase + (size_t)kk * (80 * 64);
    #pragma unroll
    for (int ks = 0; ks < 2; ks++){
      bf16x8 av = *(const bf16x8*)(wr + ks * 32);
      bf16x8 bv = *(const bf16x8*)(xr + ks * 32);
      acc = __builtin_amdgcn_mfma_f32_16x16x32_bf16(av, bv, acc, 0, 0, 0);
    }
  }
  int p = p0 + col;
  if (p < JP){
    unsigned short tb[4];
    bool live = p < L2O;
    #pragma unroll
    for (int r = 0; r < 4; r++){
      int co = co0 + g * 4 + r;
      tb[r] = live ? bf16_(relu_(acc[r] + bias[co])) : (unsigned short)0;
    }
    *(uint2*)(&h2bT[((size_t)b * JP + p) * 96 + co0 + g * 4]) = *(uint2*)tb;
    if (cog == 4){
      uint2 z = {0u, 0u};
      *(uint2*)(&h2bT[((size_t)b * JP + p) * 96 + 80 + g * 4]) = z;
    }
  }
}

// ---- conv3 via MFMA; emits f32 pconv + relu'd bf16 pconvTb[b][p][co] ----
__global__ __launch_bounds__(256) void k_c3m(const unsigned short* __restrict__ h2bT,
                        const unsigned short* __restrict__ w3r,
                        const float* __restrict__ bias, float* __restrict__ pconv,
                        unsigned short* __restrict__ pconvTb){
  int blk = blockIdx.x;
  int pt = blk % 16; int t = blk / 16;
  int cog = t % 10; int b = t / 10;
  int co0 = cog * 16;
  int wave = threadIdx.x >> 6, lane = threadIdx.x & 63;
  int col = lane & 15, g = lane >> 4;
  int p0 = pt * 64 + wave * 16;
  f32x4 acc = {0.f, 0.f, 0.f, 0.f};
  const unsigned short* wbase = w3r + (size_t)(co0 + col) * 96 + g * 8;
  const unsigned short* xbase = h2bT + (size_t)b * JP * 96 + g * 8;
  int prow = p0 + col;
  for (int kk = 0; kk < 12; kk++){
    int rp = prow + kk; if (rp > 991) rp = 991;
    const unsigned short* xr = xbase + (size_t)rp * 96;
    const unsigned short* wr = wbase + (size_t)kk * (160 * 96);
    #pragma unroll
    for (int ks = 0; ks < 3; ks++){
      bf16x8 av = *(const bf16x8*)(wr + ks * 32);
      bf16x8 bv = *(const bf16x8*)(xr + ks * 32);
      acc = __builtin_amdgcn_mfma_f32_16x16x32_bf16(av, bv, acc, 0, 0, 0);
    }
  }
  if (p0 >= L3O) return;
  int p = p0 + col;
  if (p < L3O){
    unsigned short tb[4];
    #pragma unroll
    for (int r = 0; r < 4; r++){
      int co = co0 + g * 4 + r;
      float v = acc[r] + bias[co];
      pconv[(size_t)(b * NC3 + co) * L3P + p] = v;
      tb[r] = bf16_(relu_(v));
    }
    *(uint2*)(&pconvTb[((size_t)b * JP + p) * 160 + co0 + g * 4]) = *(uint2*)tb;
  }
}

// ---- pattm: blocks 0..39 drug-att MFMA (+enc init); 40..287 protein-att MFMA ----
__global__ __launch_bounds__(256) void k_pattm(const unsigned short* __restrict__ drugb,
                        const int* __restrict__ natoms,
                        const unsigned short* __restrict__ Wdb,
                        const float* __restrict__ bd,
                        float* __restrict__ dattT, unsigned* __restrict__ enc,
                        const unsigned short* __restrict__ pconvTb,
                        const int* __restrict__ prot,
                        const unsigned short* __restrict__ Wpb,
                        const float* __restrict__ bp, float* __restrict__ pattT){
  int blk = blockIdx.x;
  int tid = threadIdx.x;
  int wave = tid >> 6, lane = tid & 63;
  int col = lane & 15, g = lane >> 4;
  if (blk < 40){
    if (blk == 0){
      for (int k = tid; k < 2 * BB * NC3; k += 256) enc[k] = 0u;
    }
    int b = blk / 10, it = blk % 10;
    int i0 = it * 16;
    const unsigned short* Xb = drugb + (size_t)b * 160 * 160;
    for (int ct = wave; ct < 10; ct += 4){
      int co0 = ct * 16;
      f32x4 acc = mfma_k160(Wdb, Xb, co0, i0, lane);
      int i = i0 + col;
      if (i < DL){
        bool act = i < natoms[b];
        #pragma unroll
        for (int r = 0; r < 4; r++){
          int co = co0 + g * 4 + r;
          dattT[(size_t)(b * NC3 + co) * DLP + i] = act ? (acc[r] + bd[co]) : 0.f;
        }
      }
    }
    return;
  }
  int q = blk - 40;
  int jt = q % 62, b = q / 62;
  int j0 = jt * 16;
  const unsigned short* Xb = pconvTb + (size_t)b * JP * 160;
  for (int ct = wave; ct < 10; ct += 4){
    int co0 = ct * 16;
    f32x4 acc = mfma_k160(Wpb, Xb, co0, j0, lane);
    int j = j0 + col;
    if (j < L3O){
      bool act = prot[b * PL + j] > 0;
      #pragma unroll
      for (int r = 0; r < 4; r++){
        int co = co0 + g * 4 + r;
        pattT[(size_t)(b * NC3 + co) * PLP + j] = act ? (acc[r] + bp[co]) : 0.f;
      }
    }
  }
}

// ---- means: emits cmeanTb bf16 [b][160][160] and pmeanTb bf16 [b][992][160] ----
__global__ __launch_bounds__(256) void k_means(const float* __restrict__ dattT,
                        const float* __restrict__ pattT,
                        unsigned short* __restrict__ cmeanTb,
                        unsigned short* __restrict__ pmeanTb){
  __shared__ __align__(16) float sda[DLP];
  __shared__ __align__(16) float spa[PLP];
  __shared__ float scm[4][DLP];
  int b = blockIdx.x / NC3, c = blockIdx.x % NC3;
  int tid = threadIdx.x;
  const float4* dr = (const float4*)(dattT + (size_t)(b * NC3 + c) * DLP);
  const float4* pr = (const float4*)(pattT + (size_t)(b * NC3 + c) * PLP);
  if (tid < DLP / 4) *(float4*)(&sda[tid * 4]) = dr[tid];
  if (tid < PLP / 4) *(float4*)(&spa[tid * 4]) = pr[tid];
  __syncthreads();
  for (int t = tid; t < 600; t += 256){
    int i = t >> 2, qq = t & 3;
    int js = qq * 244;
    int je = (qq == 3) ? L3O : js + 244;
    float v = sda[i];
    float s0 = 0.f, s1 = 0.f, s2 = 0.f, s3 = 0.f;
    const float4* p4 = (const float4*)(spa + js);
    int n4 = (je - js) >> 2;
    for (int u = 0; u < n4; u++){
      float4 p = p4[u];
      s0 += relu_(v + p.x); s1 += relu_(v + p.y);
      s2 += relu_(v + p.z); s3 += relu_(v + p.w);
    }
    for (int j = js + n4 * 4; j < je; j++) s0 += relu_(v + spa[j]);
    scm[qq][i] = (s0 + s1) + (s2 + s3);
  }
  for (int j = tid; j < L3O; j += 256){
    float v = spa[j];
    float s0 = 0.f, s1 = 0.f, s2 = 0.f, s3 = 0.f;
    const float4* d4 = (const float4*)sda;
    #pragma unroll 4
    for (int u = 0; u < 37; u++){
      float4 d = d4[u];
      s0 += relu_(v + d.x); s1 += relu_(v + d.y);
      s2 += relu_(v + d.z); s3 += relu_(v + d.w);
    }
    s0 += relu_(v + sda[148]); s1 += relu_(v + sda[149]);
    float pm = ((s0 + s1) + (s2 + s3)) * (1.f / DL);
    pmeanTb[((size_t)b * JP + j) * 160 + c] = bf16_(pm);
  }
  __syncthreads();
  if (tid < 160){
    float s = 0.f;
    if (tid < DL)
      s = ((scm[0][tid] + scm[1][tid]) + (scm[2][tid] + scm[3][tid])) * (1.f / L3O);
    cmeanTb[((size_t)b * 160 + tid) * 160 + c] = bf16_(s);
  }
}

// ---- attem: blocks 0..39 compound gate MFMA; 40..287 protein gate MFMA ----
__global__ __launch_bounds__(256) void k_attem(const unsigned short* __restrict__ cmeanTb,
                        const unsigned short* __restrict__ pmeanTb,
                        const unsigned short* __restrict__ Wattb,
                        const float* __restrict__ batt,
                        const float* __restrict__ drug,
                        const float* __restrict__ pconv, unsigned* __restrict__ enc){
  int blk = blockIdx.x;
  int tid = threadIdx.x;
  int wave = tid >> 6, lane = tid & 63;
  int col = lane & 15, g = lane >> 4;
  if (blk < 40){
    int b = blk / 10, cot = blk % 10;
    int co0 = cot * 16;
    const unsigned short* Xb = cmeanTb + (size_t)b * 160 * 160;
    float m[4];
    #pragma unroll
    for (int r = 0; r < 4; r++) m[r] = NINF;
    for (int it = wave; it < 10; it += 4){
      int i0 = it * 16;
      f32x4 acc = mfma_k160(Wattb, Xb, co0, i0, lane);
      int i = i0 + col;
      if (i < DL){
        #pragma unroll
        for (int r = 0; r < 4; r++){
          int co = co0 + g * 4 + r;
          float gate = 1.f / (1.f + expf(-(acc[r] + batt[co])));
          float val = drug[((size_t)b * DL + i) * 160 + co] * (0.5f + gate);
          m[r] = fmaxf(m[r], val);
        }
      }
    }
    #pragma unroll
    for (int r = 0; r < 4; r++){
      #pragma unroll
      for (int off = 1; off < 16; off <<= 1)
        m[r] = fmaxf(m[r], __shfl_xor(m[r], off, 64));
    }
    if (col == 0){
      #pragma unroll
      for (int r = 0; r < 4; r++)
        atomicMax(&enc[b * NC3 + co0 + g * 4 + r], fenc(m[r]));
    }
    return;
  }
  int q = blk - 40;
  int jt = q % 62, b = q / 62;
  int j0 = jt * 16;
  const unsigned short* Xb = pmeanTb + (size_t)b * JP * 160;
  for (int ct = wave; ct < 10; ct += 4){
    int co0 = ct * 16;
    f32x4 acc = mfma_k160(Wattb, Xb, co0, j0, lane);
    int j = j0 + col;
    float m[4];
    #pragma unroll
    for (int r = 0; r < 4; r++){
      int co = co0 + g * 4 + r;
      if (j < L3O){
        float gate = 1.f / (1.f + expf(-(acc[r] + batt[co])));
        float pv = relu_(pconv[(size_t)(b * NC3 + co) * L3P + j]);
        m[r] = pv * (0.5f + gate);
      } else m[r] = NINF;
    }
    #pragma unroll
    for (int r = 0; r < 4; r++){
      #pragma unroll
      for (int off = 1; off < 16; off <<= 1)
        m[r] = fmaxf(m[r], __shfl_xor(m[r], off, 64));
    }
    if (col == 0){
      #pragma unroll
      for (int r = 0; r < 4; r++)
        atomicMax(&enc[BB * NC3 + b * NC3 + co0 + g * 4 + r], fenc(m[r]));
    }
  }
}

// ---- MLP 1: 320 -> 1024 ----
__global__ __launch_bounds__(256) void k_mlp1(const unsigned* __restrict__ enc,
                        const float* __restrict__ W1, const float* __restrict__ bf1,
                        float* __restrict__ f1){
  int b = blockIdx.x >> 6, og = blockIdx.x & 63;
  int o = og * 16 + (threadIdx.x >> 4);
  int q = threadIdx.x & 15;
  const float4* wr = (const float4*)(W1 + (size_t)o * 320);
  float4 a = make_float4(0.f, 0.f, 0.f, 0.f);
  #pragma unroll
  for (int mi = 0; mi < 5; mi++){
    int k4 = q + mi * 16;
    int k = k4 * 4;
    const unsigned* e = (k < 160) ? (enc + b * NC3 + k)
                                  : (enc + BB * NC3 + b * NC3 + (k - 160));
    float4 wv = wr[k4];
    a.x = fmaf(fdec(e[0]), wv.x, a.x);
    a.y = fmaf(fdec(e[1]), wv.y, a.y);
    a.z = fmaf(fdec(e[2]), wv.z, a.z);
    a.w = fmaf(fdec(e[3]), wv.w, a.w);
  }
  float r = a.x + a.y + a.z + a.w;
  r += __shfl_xor(r, 1, 64); r += __shfl_xor(r, 2, 64);
  r += __shfl_xor(r, 4, 64); r += __shfl_xor(r, 8, 64);
  if (q == 0) f1[b * 1024 + o] = lrelu_(r + bf1[o]);
}

// ---- MLP 2: 1024 -> 1024 ----
__global__ __launch_bounds__(256) void k_mlp2(const float* __restrict__ x,
                        const float* __restrict__ W, const float* __restrict__ bias,
                        float* __restrict__ y){
  int b = blockIdx.x >> 6, og = blockIdx.x & 63;
  int o = og * 16 + (threadIdx.x >> 4);
  int q = threadIdx.x & 15;
  const float4* wr = (const float4*)(W + (size_t)o * 1024);
  const float4* xr = (const float4*)(x + b * 1024);
  float4 a = make_float4(0.f, 0.f, 0.f, 0.f);
  #pragma unroll
  for (int mi = 0; mi < 16; mi++){
    int k4 = q + mi * 16;
    float4 wv = wr[k4], xv = xr[k4];
    a.x = fmaf(xv.x, wv.x, a.x);
    a.y = fmaf(xv.y, wv.y, a.y);
    a.z = fmaf(xv.z, wv.z, a.z);
    a.w = fmaf(xv.w, wv.w, a.w);
  }
  float r = a.x + a.y + a.z + a.w;
  r += __shfl_xor(r, 1, 64); r += __shfl_xor(r, 2, 64);
  r += __shfl_xor(r, 4, 64); r += __shfl_xor(r, 8, 64);
  if (q == 0) y[b * 1024 + o] = lrelu_(r + bias[o]);
}

// ---- MLP 3: 1024 -> 512 ----
__global__ __launch_bounds__(256) void k_mlp3(const float* __restrict__ x,
                        const float* __restrict__ W, const float* __restrict__ bias,
                        float* __restrict__ y){
  int b = blockIdx.x >> 5, og = blockIdx.x & 31;
  int o = og * 16 + (threadIdx.x >> 4);
  int q = threadIdx.x & 15;
  const float4* wr = (const float4*)(W + (size_t)o * 1024);
  const float4* xr = (const float4*)(x + b * 1024);
  float4 a = make_float4(0.f, 0.f, 0.f, 0.f);
  #pragma unroll
  for (int mi = 0; mi < 16; mi++){
    int k4 = q + mi * 16;
    float4 wv = wr[k4], xv = xr[k4];
    a.x = fmaf(xv.x, wv.x, a.x);
    a.y = fmaf(xv.y, wv.y, a.y);
    a.z = fmaf(xv.z, wv.z, a.z);
    a.w = fmaf(xv.w, wv.w, a.w);
  }
  float r = a.x + a.y + a.z + a.w;
  r += __shfl_xor(r, 1, 64); r += __shfl_xor(r, 2, 64);
  r += __shfl_xor(r, 4, 64); r += __shfl_xor(r, 8, 64);
  if (q == 0) y[b * 512 + o] = lrelu_(r + bias[o]);
}

// ---- MLP out: 512 -> 2 ----
__global__ void k_mlp4(const float* __restrict__ f3, const float* __restrict__ Wo,
                       const float* __restrict__ bo, float* __restrict__ out){
  int tid = threadIdx.x;
  int g = tid >> 5, lane = tid & 31;
  int b = g >> 1, o = g & 1;
  const float4* xr = (const float4*)(f3 + b * 512);
  const float4* wr = (const float4*)(Wo + o * 512);
  float4 a = make_float4(0.f, 0.f, 0.f, 0.f);
  #pragma unroll
  for (int mI = 0; mI < 4; mI++){
    int k4 = lane + mI * 32;
    float4 xv = xr[k4], wv = wr[k4];
    a.x = fmaf(xv.x, wv.x, a.x);
    a.y = fmaf(xv.y, wv.y, a.y);
    a.z = fmaf(xv.z, wv.z, a.z);
    a.w = fmaf(xv.w, wv.w, a.w);
  }
  float r = a.x + a.y + a.z + a.w;
  for (int off = 16; off; off >>= 1) r += __shfl_xor(r, off, 64);
  if (lane == 0) out[b * 2 + o] = r + bo[o];
}

extern "C" void kernel_launch(void* const* d_in, const int* in_sizes, int n_in,
                              void* d_out, int out_size, void* d_ws, size_t ws_size,
                              hipStream_t stream) {
  const float* drug  = (const float*)d_in[0];
  const int*   natoms= (const int*)d_in[1];
  const int*   prot  = (const int*)d_in[2];
  const float* emb   = (const float*)d_in[3];
  const float* w1    = (const float*)d_in[4];
  const float* b1    = (const float*)d_in[5];
  const float* w2    = (const float*)d_in[6];
  const float* b2    = (const float*)d_in[7];
  const float* w3    = (const float*)d_in[8];
  const float* b3    = (const float*)d_in[9];
  const float* Wd    = (const float*)d_in[10];
  const float* bd    = (const float*)d_in[11];
  const float* Wp    = (const float*)d_in[12];
  const float* bp    = (const float*)d_in[13];
  const float* Watt  = (const float*)d_in[14];
  const float* batt  = (const float*)d_in[15];
  const float* W1    = (const float*)d_in[16];
  const float* bf1   = (const float*)d_in[17];
  const float* W2    = (const float*)d_in[18];
  const float* bf2   = (const float*)d_in[19];
  const float* W3    = (const float*)d_in[20];
  const float* bf3   = (const float*)d_in[21];
  const float* Wo    = (const float*)d_in[22];
  const float* bo    = (const float*)d_in[23];
  float* out = (float*)d_out;

  float* ws = (float*)d_ws;
  float* f1     = ws;                        // 4096
  float* f2     = ws + 4096;                 // 4096
  float* f3     = ws + 8192;                 // 2048
  float* dattT  = ws + 10240;                // 97280
  float* pattT  = ws + 107520;               // 629760
  float* pconv  = ws + 737280;               // 627200
  unsigned* enc = (unsigned*)(ws + 1364480); // 1280 u32
  float* projG  = ws + 1364864;              // 4186
  unsigned short* h1bT    = (unsigned short*)(ws + 1369088); // 256000 bf16
  unsigned short* w2r     = (unsigned short*)(ws + 1497088); // 40960 bf16
  unsigned short* h2bT    = (unsigned short*)(ws + 1517568); // 380928 bf16
  unsigned short* w3r     = (unsigned short*)(ws + 1708032); // 184320 bf16
  unsigned short* pconvTb = (unsigned short*)(ws + 1800192); // 634880 bf16
  unsigned short* pmeanTb = (unsigned short*)(ws + 2117632); // 634880 bf16
  unsigned short* cmeanTb = (unsigned short*)(ws + 2435072); // 102400 bf16
  unsigned short* drugb   = (unsigned short*)(ws + 2486272); // 102400 bf16
  unsigned short* Wpb     = (unsigned short*)(ws + 2537472); // 25600 bf16
  unsigned short* Wattb   = (unsigned short*)(ws + 2550272); // 25600 bf16
  unsigned short* Wdb     = (unsigned short*)(ws + 2563072); // 25600 bf16

  k_prep  <<<1597, 256, 0, stream>>>(emb, w1, projG, w3, w3r, Wp, Wpb,
                                     Watt, Wattb, Wd, Wdb, w2, w2r, drug, drugb);
  k_conv1 <<<500, 256, 0, stream>>>(prot, projG, b1, h1bT);
  k_c2m   <<<320, 256, 0, stream>>>(h1bT, w2r, b2, h2bT);
  k_c3m   <<<640, 256, 0, stream>>>(h2bT, w3r, b3, pconv, pconvTb);
  k_pattm <<<288, 256, 0, stream>>>(drugb, natoms, Wdb, bd, dattT, enc,
                                    pconvTb, prot, Wpb, bp, pattT);
  k_means <<<BB * NC3, 256, 0, stream>>>(dattT, pattT, cmeanTb, pmeanTb);
  k_attem <<<288, 256, 0, stream>>>(cmeanTb, pmeanTb, Wattb, batt, drug,
                                    pconv, enc);
  k_mlp1  <<<256, 256, 0, stream>>>(enc, W1, bf1, f1);
  k_mlp2  <<<256, 256, 0, stream>>>(f1, W2, bf2, f2);
  k_mlp3  <<<128, 256, 0, stream>>>(f2, W3, bf3, f3);
  k_mlp4  <<<1, 256, 0, stream>>>(f3, Wo, bo, out);
}